// Round 1
// baseline (1361.761 us; speedup 1.0000x reference)
//
#include <hip/hip_runtime.h>

#define NEG_SLOPE 0.2f

// ---------------- CSR build ----------------

__global__ void zero_int_kernel(int* __restrict__ p, int n) {
    int i = blockIdx.x * blockDim.x + threadIdx.x;
    if (i < n) p[i] = 0;
}

__global__ void hist_kernel(const int* __restrict__ dst, int E, int* __restrict__ deg) {
    int i = blockIdx.x * blockDim.x + threadIdx.x;
    if (i < E) atomicAdd(&deg[dst[i]], 1);
}

__global__ __launch_bounds__(1024) void scan_kernel(const int* __restrict__ deg,
                                                    int* __restrict__ rowptr, int N) {
    __shared__ int sums[1024];
    int t = threadIdx.x;
    int chunk = (N + 1023) / 1024;
    int lo = t * chunk;
    int hi = min(lo + chunk, N);
    int s = 0;
    for (int i = lo; i < hi; ++i) s += deg[i];
    sums[t] = s;
    __syncthreads();
    // Hillis-Steele inclusive scan
    for (int off = 1; off < 1024; off <<= 1) {
        int v = (t >= off) ? sums[t - off] : 0;
        __syncthreads();
        sums[t] += v;
        __syncthreads();
    }
    int run = sums[t] - s;  // exclusive prefix
    for (int i = lo; i < hi; ++i) { rowptr[i] = run; run += deg[i]; }
    if (hi == N) rowptr[N] = run;
}

__global__ void scatter_kernel(const int* __restrict__ src, const int* __restrict__ dst, int E,
                               const int* __restrict__ rowptr, int* __restrict__ cursor,
                               int* __restrict__ csr_src) {
    int i = blockIdx.x * blockDim.x + threadIdx.x;
    if (i < E) {
        int d = dst[i];
        int p = atomicAdd(&cursor[d], 1);
        csr_src[rowptr[d] + p] = src[i];
    }
}

// ---------------- GEMM1: h1 = x[N,512] @ W1[512,64] ----------------

#define BM 64
#define BN 64
#define BK 32

__global__ __launch_bounds__(256) void gemm1_kernel(const float* __restrict__ x,
                                                    const float* __restrict__ W,
                                                    float* __restrict__ h, int N) {
    __shared__ float As[BK][BM + 4];
    __shared__ float Bs[BK][BN + 4];
    int tid = threadIdx.x;
    int row0 = blockIdx.x * BM;
    int ty = tid >> 4;          // 0..15
    int tx = tid & 15;          // 0..15
    float acc[4][4] = {};
    for (int kt = 0; kt < 512; kt += BK) {
        // A tile: 64 rows x 32 k (transposed into LDS)
        int r = tid >> 3;               // 0..31
        int kk = (tid & 7) * 4;         // 0..28
        #pragma unroll
        for (int rr = 0; rr < BM; rr += 32) {
            int grow = row0 + r + rr;
            float4 v = make_float4(0.f, 0.f, 0.f, 0.f);
            if (grow < N)
                v = *reinterpret_cast<const float4*>(&x[(size_t)grow * 512 + kt + kk]);
            As[kk + 0][r + rr] = v.x;
            As[kk + 1][r + rr] = v.y;
            As[kk + 2][r + rr] = v.z;
            As[kk + 3][r + rr] = v.w;
        }
        // B tile: 32 k x 64 cols
        int br = tid >> 4;              // 0..15
        int bc = (tid & 15) * 4;        // 0..60
        #pragma unroll
        for (int rr = 0; rr < BK; rr += 16) {
            float4 v = *reinterpret_cast<const float4*>(&W[(size_t)(kt + br + rr) * 64 + bc]);
            Bs[br + rr][bc + 0] = v.x;
            Bs[br + rr][bc + 1] = v.y;
            Bs[br + rr][bc + 2] = v.z;
            Bs[br + rr][bc + 3] = v.w;
        }
        __syncthreads();
        #pragma unroll
        for (int k = 0; k < BK; ++k) {
            float a[4], b[4];
            #pragma unroll
            for (int i = 0; i < 4; ++i) a[i] = As[k][ty * 4 + i];
            #pragma unroll
            for (int j = 0; j < 4; ++j) b[j] = Bs[k][tx * 4 + j];
            #pragma unroll
            for (int i = 0; i < 4; ++i)
                #pragma unroll
                for (int j = 0; j < 4; ++j) acc[i][j] += a[i] * b[j];
        }
        __syncthreads();
    }
    #pragma unroll
    for (int i = 0; i < 4; ++i) {
        int grow = row0 + ty * 4 + i;
        if (grow < N) {
            #pragma unroll
            for (int j = 0; j < 4; ++j) h[(size_t)grow * 64 + tx * 4 + j] = acc[i][j];
        }
    }
}

// ---------------- alpha_src/alpha_dst for layer 1 ----------------

__global__ void alphas1_kernel(const float* __restrict__ h1, const float* __restrict__ a_src,
                               const float* __restrict__ a_dst, float* __restrict__ as1,
                               float* __restrict__ ad1, int N) {
    int i = blockIdx.x * blockDim.x + threadIdx.x;   // over N*8
    if (i >= N * 8) return;
    int n = i >> 3, hh = i & 7;
    const float4* hp = reinterpret_cast<const float4*>(&h1[(size_t)n * 64 + hh * 8]);
    float4 v0 = hp[0], v1 = hp[1];
    const float* asw = &a_src[hh * 8];
    const float* adw = &a_dst[hh * 8];
    float s = v0.x * asw[0] + v0.y * asw[1] + v0.z * asw[2] + v0.w * asw[3] +
              v1.x * asw[4] + v1.y * asw[5] + v1.z * asw[6] + v1.w * asw[7];
    float d = v0.x * adw[0] + v0.y * adw[1] + v0.z * adw[2] + v0.w * adw[3] +
              v1.x * adw[4] + v1.y * adw[5] + v1.z * adw[6] + v1.w * adw[7];
    as1[i] = s;
    ad1[i] = d;
}

// ---------------- layer-1 segment softmax + aggregation (one wave per dst) ----------------

__global__ __launch_bounds__(256) void attn1_kernel(
    const float* __restrict__ h1, const float* __restrict__ as1, const float* __restrict__ ad1,
    const int* __restrict__ rowptr, const int* __restrict__ csr_src,
    const float* __restrict__ b1, float* __restrict__ helu, int N) {
    int wv = threadIdx.x >> 6;
    int lane = threadIdx.x & 63;
    int d = blockIdx.x * 4 + wv;
    if (d >= N) return;
    int beg = rowptr[d];
    int edeg = rowptr[d + 1] - beg;
    int tot = edeg + 1;  // + virtual self loop (src = d)

    // phase 1: online max/sum per head. lane -> (e8 = lane>>3 edge slot, h = lane&7)
    int h = lane & 7;
    int e8 = lane >> 3;
    float adh = ad1[d * 8 + h];
    float m = -1e30f, s = 0.f;
    for (int p = e8; p < tot; p += 8) {
        int src = (p < edeg) ? csr_src[beg + p] : d;
        float e = as1[src * 8 + h] + adh;
        e = (e > 0.f) ? e : NEG_SLOPE * e;
        if (e > m) {
            s = s * __expf(m - e) + 1.f;
            m = e;
        } else {
            s += __expf(e - m);
        }
    }
    #pragma unroll
    for (int mask = 8; mask < 64; mask <<= 1) {
        float om = __shfl_xor(m, mask);
        float os = __shfl_xor(s, mask);
        float nm = fmaxf(m, om);
        s = s * __expf(m - nm) + os * __expf(om - nm);
        m = nm;
    }
    // phase 2: lane -> (h2 = lane>>3 head, dd = lane&7 dim)
    int h2 = lane >> 3;
    float mh = __shfl(m, h2);     // lane h2 (e8=0) holds head-h2 result
    float denom = __shfl(s, h2) + 1e-16f;
    float adh2 = ad1[d * 8 + h2];
    float acc = 0.f;
    for (int p = 0; p < tot; ++p) {
        int src = (p < edeg) ? csr_src[beg + p] : d;
        float e = as1[src * 8 + h2] + adh2;
        e = (e > 0.f) ? e : NEG_SLOPE * e;
        float w = __expf(e - mh) / denom;
        acc += w * h1[(size_t)src * 64 + lane];
    }
    float v = acc + b1[lane];
    v = (v > 0.f) ? v : (__expf(v) - 1.f);   // ELU
    helu[(size_t)d * 64 + lane] = v;
}

// ---------------- GEMM2 (64x64) + alpha2, one wave per row ----------------

__global__ __launch_bounds__(256) void gemm2_kernel(
    const float* __restrict__ helu, const float* __restrict__ W2,
    const float* __restrict__ a_src2, const float* __restrict__ a_dst2,
    float* __restrict__ h2, float* __restrict__ as2, float* __restrict__ ad2, int N) {
    __shared__ float Ws[64 * 64];
    __shared__ float asw[64], adw[64];
    int tid = threadIdx.x;
    for (int i = tid; i < 64 * 64; i += 256) Ws[i] = W2[i];
    if (tid < 64) { asw[tid] = a_src2[tid]; adw[tid] = a_dst2[tid]; }
    __syncthreads();
    int lane = tid & 63, wv = tid >> 6;
    int stride = gridDim.x * 4;
    for (int row = blockIdx.x * 4 + wv; row < N; row += stride) {
        float hv = helu[(size_t)row * 64 + lane];
        float acc = 0.f;
        #pragma unroll
        for (int k = 0; k < 64; ++k) {
            float v = __shfl(hv, k);
            acc += v * Ws[k * 64 + lane];
        }
        h2[(size_t)row * 64 + lane] = acc;
        float pa = acc * asw[lane];
        float pb = acc * adw[lane];
        #pragma unroll
        for (int mask = 1; mask < 64; mask <<= 1) {
            pa += __shfl_xor(pa, mask);
            pb += __shfl_xor(pb, mask);
        }
        if (lane == 0) { as2[row] = pa; ad2[row] = pb; }
    }
}

// ---------------- layer-2 attention + log_softmax (one wave per dst) ----------------

__global__ __launch_bounds__(256) void attn2_kernel(
    const float* __restrict__ h2, const float* __restrict__ as2, const float* __restrict__ ad2,
    const int* __restrict__ rowptr, const int* __restrict__ csr_src,
    const float* __restrict__ b2, float* __restrict__ out, int N) {
    int wv = threadIdx.x >> 6;
    int lane = threadIdx.x & 63;
    int d = blockIdx.x * 4 + wv;
    if (d >= N) return;
    int beg = rowptr[d];
    int edeg = rowptr[d + 1] - beg;
    int tot = edeg + 1;
    float add = ad2[d];
    float m = -1e30f, s = 0.f;
    for (int p = lane; p < tot; p += 64) {
        int src = (p < edeg) ? csr_src[beg + p] : d;
        float e = as2[src] + add;
        e = (e > 0.f) ? e : NEG_SLOPE * e;
        if (e > m) {
            s = s * __expf(m - e) + 1.f;
            m = e;
        } else {
            s += __expf(e - m);
        }
    }
    #pragma unroll
    for (int mask = 1; mask < 64; mask <<= 1) {
        float om = __shfl_xor(m, mask);
        float os = __shfl_xor(s, mask);
        float nm = fmaxf(m, om);
        s = s * __expf(m - nm) + os * __expf(om - nm);
        m = nm;
    }
    float denom = s + 1e-16f;
    float acc = 0.f;
    for (int p = 0; p < tot; ++p) {
        int src = (p < edeg) ? csr_src[beg + p] : d;
        float e = as2[src] + add;
        e = (e > 0.f) ? e : NEG_SLOPE * e;
        float w = __expf(e - m) / denom;
        acc += w * h2[(size_t)src * 64 + lane];
    }
    float o = acc + b2[lane];
    // log_softmax over 64 lanes
    float mx = o;
    #pragma unroll
    for (int mask = 1; mask < 64; mask <<= 1) mx = fmaxf(mx, __shfl_xor(mx, mask));
    float ex = __expf(o - mx);
    float sm = ex;
    #pragma unroll
    for (int mask = 1; mask < 64; mask <<= 1) sm += __shfl_xor(sm, mask);
    out[(size_t)d * 64 + lane] = o - mx - logf(sm);
}

// ---------------- launch ----------------

extern "C" void kernel_launch(void* const* d_in, const int* in_sizes, int n_in,
                              void* d_out, int out_size, void* d_ws, size_t ws_size,
                              hipStream_t stream) {
    const float* x      = (const float*)d_in[0];
    const int*   ei     = (const int*)d_in[1];
    const float* W1     = (const float*)d_in[2];
    const float* a_src1 = (const float*)d_in[3];
    const float* a_dst1 = (const float*)d_in[4];
    const float* b1     = (const float*)d_in[5];
    const float* W2     = (const float*)d_in[6];
    const float* a_src2 = (const float*)d_in[7];
    const float* a_dst2 = (const float*)d_in[8];
    const float* b2     = (const float*)d_in[9];

    int N = in_sizes[0] / 512;
    int E = in_sizes[1] / 2;
    const int* src = ei;
    const int* dst = ei + E;

    char* w = (char*)d_ws;
    size_t off = 0;
    auto alloc = [&](size_t bytes) -> void* {
        off = (off + 255) & ~(size_t)255;
        void* p = w + off;
        off += bytes;
        return p;
    };
    int* deg    = (int*)alloc((size_t)2 * N * sizeof(int));
    int* cursor = deg + N;
    int* rowptr = (int*)alloc((size_t)(N + 1) * sizeof(int));
    int* csr    = (int*)alloc((size_t)E * sizeof(int));
    float* h1   = (float*)alloc((size_t)N * 64 * sizeof(float));
    float* as1  = (float*)alloc((size_t)N * 8 * sizeof(float));
    float* ad1  = (float*)alloc((size_t)N * 8 * sizeof(float));
    float* helu = (float*)alloc((size_t)N * 64 * sizeof(float));
    // aliases (h1/as1/ad1 are dead after attn1)
    float* h2  = h1;
    float* as2 = as1;
    float* ad2 = ad1;

    // CSR build
    zero_int_kernel<<<(2 * N + 255) / 256, 256, 0, stream>>>(deg, 2 * N);
    hist_kernel<<<(E + 255) / 256, 256, 0, stream>>>(dst, E, deg);
    scan_kernel<<<1, 1024, 0, stream>>>(deg, rowptr, N);
    scatter_kernel<<<(E + 255) / 256, 256, 0, stream>>>(src, dst, E, rowptr, cursor, csr);

    // layer 1
    gemm1_kernel<<<(N + BM - 1) / BM, 256, 0, stream>>>(x, W1, h1, N);
    alphas1_kernel<<<(N * 8 + 255) / 256, 256, 0, stream>>>(h1, a_src1, a_dst1, as1, ad1, N);
    attn1_kernel<<<(N + 3) / 4, 256, 0, stream>>>(h1, as1, ad1, rowptr, csr, b1, helu, N);

    // layer 2
    gemm2_kernel<<<2048, 256, 0, stream>>>(helu, W2, a_src2, a_dst2, h2, as2, ad2, N);
    attn2_kernel<<<(N + 3) / 4, 256, 0, stream>>>(h2, as2, ad2, rowptr, csr, b2, (float*)d_out, N);
}

// Round 2
// 999.755 us; speedup vs baseline: 1.3621x; 1.3621x over previous
//
#include <hip/hip_runtime.h>

#define NEG_SLOPE 0.2f

// ---------------- CSR build ----------------

__global__ void zero_int_kernel(int* __restrict__ p, int n) {
    int i = blockIdx.x * blockDim.x + threadIdx.x;
    if (i < n) p[i] = 0;
}

__global__ void hist_kernel(const int* __restrict__ dst, int E, int* __restrict__ deg) {
    int i = blockIdx.x * blockDim.x + threadIdx.x;
    if (i < E) atomicAdd(&deg[dst[i]], 1);
}

__global__ __launch_bounds__(1024) void scan_kernel(const int* __restrict__ deg,
                                                    int* __restrict__ rowptr, int N) {
    __shared__ int sums[1024];
    int t = threadIdx.x;
    int chunk = (N + 1023) / 1024;
    int lo = t * chunk;
    int hi = min(lo + chunk, N);
    int s = 0;
    for (int i = lo; i < hi; ++i) s += deg[i];
    sums[t] = s;
    __syncthreads();
    for (int off = 1; off < 1024; off <<= 1) {
        int v = (t >= off) ? sums[t - off] : 0;
        __syncthreads();
        sums[t] += v;
        __syncthreads();
    }
    int run = sums[t] - s;  // exclusive prefix
    for (int i = lo; i < hi; ++i) { rowptr[i] = run; run += deg[i]; }
    if (hi == N) rowptr[N] = run;
}

__global__ void scatter_kernel(const int* __restrict__ src, const int* __restrict__ dst, int E,
                               const int* __restrict__ rowptr, int* __restrict__ cursor,
                               int* __restrict__ csr_src) {
    int i = blockIdx.x * blockDim.x + threadIdx.x;
    if (i < E) {
        int d = dst[i];
        int p = atomicAdd(&cursor[d], 1);
        csr_src[rowptr[d] + p] = src[i];
    }
}

// ---------------- GEMM1: h1 = x[N,512] @ W1[512,64] ----------------

#define BM 64
#define BN 64
#define BK 32

__global__ __launch_bounds__(256) void gemm1_kernel(const float* __restrict__ x,
                                                    const float* __restrict__ W,
                                                    float* __restrict__ h, int N) {
    __shared__ float As[BK][BM + 4];
    __shared__ float Bs[BK][BN + 4];
    int tid = threadIdx.x;
    int row0 = blockIdx.x * BM;
    int ty = tid >> 4;          // 0..15
    int tx = tid & 15;          // 0..15
    float acc[4][4] = {};
    for (int kt = 0; kt < 512; kt += BK) {
        int r = tid >> 3;               // 0..31
        int kk = (tid & 7) * 4;         // 0..28
        #pragma unroll
        for (int rr = 0; rr < BM; rr += 32) {
            int grow = row0 + r + rr;
            float4 v = make_float4(0.f, 0.f, 0.f, 0.f);
            if (grow < N)
                v = *reinterpret_cast<const float4*>(&x[(size_t)grow * 512 + kt + kk]);
            As[kk + 0][r + rr] = v.x;
            As[kk + 1][r + rr] = v.y;
            As[kk + 2][r + rr] = v.z;
            As[kk + 3][r + rr] = v.w;
        }
        int br = tid >> 4;              // 0..15
        int bc = (tid & 15) * 4;        // 0..60
        #pragma unroll
        for (int rr = 0; rr < BK; rr += 16) {
            float4 v = *reinterpret_cast<const float4*>(&W[(size_t)(kt + br + rr) * 64 + bc]);
            Bs[br + rr][bc + 0] = v.x;
            Bs[br + rr][bc + 1] = v.y;
            Bs[br + rr][bc + 2] = v.z;
            Bs[br + rr][bc + 3] = v.w;
        }
        __syncthreads();
        #pragma unroll
        for (int k = 0; k < BK; ++k) {
            float a[4], b[4];
            #pragma unroll
            for (int i = 0; i < 4; ++i) a[i] = As[k][ty * 4 + i];
            #pragma unroll
            for (int j = 0; j < 4; ++j) b[j] = Bs[k][tx * 4 + j];
            #pragma unroll
            for (int i = 0; i < 4; ++i)
                #pragma unroll
                for (int j = 0; j < 4; ++j) acc[i][j] += a[i] * b[j];
        }
        __syncthreads();
    }
    #pragma unroll
    for (int i = 0; i < 4; ++i) {
        int grow = row0 + ty * 4 + i;
        if (grow < N) {
            #pragma unroll
            for (int j = 0; j < 4; ++j) h[(size_t)grow * 64 + tx * 4 + j] = acc[i][j];
        }
    }
}

// ---------------- alpha_src/alpha_dst for layer 1 ----------------

__global__ void alphas1_kernel(const float* __restrict__ h1, const float* __restrict__ a_src,
                               const float* __restrict__ a_dst, float* __restrict__ as1,
                               float* __restrict__ ad1, int N) {
    int i = blockIdx.x * blockDim.x + threadIdx.x;   // over N*8
    if (i >= N * 8) return;
    int n = i >> 3, hh = i & 7;
    const float4* hp = reinterpret_cast<const float4*>(&h1[(size_t)n * 64 + hh * 8]);
    float4 v0 = hp[0], v1 = hp[1];
    const float* asw = &a_src[hh * 8];
    const float* adw = &a_dst[hh * 8];
    float s = v0.x * asw[0] + v0.y * asw[1] + v0.z * asw[2] + v0.w * asw[3] +
              v1.x * asw[4] + v1.y * asw[5] + v1.z * asw[6] + v1.w * asw[7];
    float d = v0.x * adw[0] + v0.y * adw[1] + v0.z * adw[2] + v0.w * adw[3] +
              v1.x * adw[4] + v1.y * adw[5] + v1.z * adw[6] + v1.w * adw[7];
    as1[i] = s;
    ad1[i] = d;
}

// ---------------- layer-1 attention (one wave per dst, 4 edges/iter) ----------------

__global__ __launch_bounds__(256) void attn1_kernel(
    const float* __restrict__ h1, const float* __restrict__ as1, const float* __restrict__ ad1,
    const int* __restrict__ rowptr, const int* __restrict__ csr_src,
    const float* __restrict__ b1, float* __restrict__ helu, int N) {
    int wv = threadIdx.x >> 6;
    int lane = threadIdx.x & 63;
    int d = blockIdx.x * 4 + wv;
    if (d >= N) return;
    int beg = rowptr[d];
    int edeg = rowptr[d + 1] - beg;
    int tot = edeg + 1;  // + virtual self loop (src = d)

    // phase 1: online max/sum per head. lane = (e8 = lane>>3 edge slot, h = lane&7)
    int h = lane & 7;
    int e8 = lane >> 3;
    float adh = ad1[d * 8 + h];
    float m = -1e30f, s = 0.f;
    for (int p = e8; p < tot; p += 8) {
        int sn = (p < edeg) ? csr_src[beg + p] : d;
        float e = as1[sn * 8 + h] + adh;
        e = fmaxf(e, NEG_SLOPE * e);
        float nm = fmaxf(m, e);
        s = s * __expf(m - nm) + __expf(e - nm);
        m = nm;
    }
    #pragma unroll
    for (int mask = 8; mask < 64; mask <<= 1) {
        float om = __shfl_xor(m, mask);
        float os = __shfl_xor(s, mask);
        float nm = fmaxf(m, om);
        s = s * __expf(m - nm) + os * __expf(om - nm);
        m = nm;
    }
    // phase 2: lane = (g = lane>>4 edge slot, q = lane&15 dim quad), head = q>>1
    int q = lane & 15;
    int g = lane >> 4;
    int hh = q >> 1;
    float mh = __shfl(m, hh);
    float inv = 1.f / (__shfl(s, hh) + 1e-16f);
    float adh2 = ad1[d * 8 + hh];
    float acc0 = 0.f, acc1 = 0.f, acc2 = 0.f, acc3 = 0.f;
    for (int p0 = 0; p0 < tot; p0 += 4) {
        int p = p0 + g;
        int sn = (p < edeg) ? csr_src[beg + p] : d;
        float w = 0.f;
        if (p < tot) {
            float e = as1[sn * 8 + hh] + adh2;
            e = fmaxf(e, NEG_SLOPE * e);
            w = __expf(e - mh);
        }
        const float4 hv = *reinterpret_cast<const float4*>(&h1[(size_t)sn * 64 + q * 4]);
        acc0 = fmaf(w, hv.x, acc0);
        acc1 = fmaf(w, hv.y, acc1);
        acc2 = fmaf(w, hv.z, acc2);
        acc3 = fmaf(w, hv.w, acc3);
    }
    #pragma unroll
    for (int mask = 16; mask < 64; mask <<= 1) {
        acc0 += __shfl_xor(acc0, mask);
        acc1 += __shfl_xor(acc1, mask);
        acc2 += __shfl_xor(acc2, mask);
        acc3 += __shfl_xor(acc3, mask);
    }
    if (lane < 16) {
        const float4 bv = *reinterpret_cast<const float4*>(&b1[q * 4]);
        float4 o;
        o.x = fmaf(acc0, inv, bv.x);
        o.y = fmaf(acc1, inv, bv.y);
        o.z = fmaf(acc2, inv, bv.z);
        o.w = fmaf(acc3, inv, bv.w);
        o.x = (o.x > 0.f) ? o.x : (__expf(o.x) - 1.f);
        o.y = (o.y > 0.f) ? o.y : (__expf(o.y) - 1.f);
        o.z = (o.z > 0.f) ? o.z : (__expf(o.z) - 1.f);
        o.w = (o.w > 0.f) ? o.w : (__expf(o.w) - 1.f);
        *reinterpret_cast<float4*>(&helu[(size_t)d * 64 + q * 4]) = o;
    }
}

// ---------------- GEMM2 (64x64) + alpha2, one wave per row ----------------

__global__ __launch_bounds__(256) void gemm2_kernel(
    const float* __restrict__ helu, const float* __restrict__ W2,
    const float* __restrict__ a_src2, const float* __restrict__ a_dst2,
    float* __restrict__ h2, float* __restrict__ as2, float* __restrict__ ad2, int N) {
    __shared__ float Ws[64 * 64];
    __shared__ float asw[64], adw[64];
    int tid = threadIdx.x;
    for (int i = tid; i < 64 * 64; i += 256) Ws[i] = W2[i];
    if (tid < 64) { asw[tid] = a_src2[tid]; adw[tid] = a_dst2[tid]; }
    __syncthreads();
    int lane = tid & 63, wv = tid >> 6;
    int stride = gridDim.x * 4;
    for (int row = blockIdx.x * 4 + wv; row < N; row += stride) {
        float hv = helu[(size_t)row * 64 + lane];
        float acc = 0.f;
        #pragma unroll
        for (int k = 0; k < 64; ++k) {
            float v = __shfl(hv, k);
            acc += v * Ws[k * 64 + lane];
        }
        h2[(size_t)row * 64 + lane] = acc;
        float pa = acc * asw[lane];
        float pb = acc * adw[lane];
        #pragma unroll
        for (int mask = 1; mask < 64; mask <<= 1) {
            pa += __shfl_xor(pa, mask);
            pb += __shfl_xor(pb, mask);
        }
        if (lane == 0) { as2[row] = pa; ad2[row] = pb; }
    }
}

// ---------------- layer-2 attention + log_softmax (one wave per dst, 4 edges/iter) ----------------

__global__ __launch_bounds__(256) void attn2_kernel(
    const float* __restrict__ h2, const float* __restrict__ as2, const float* __restrict__ ad2,
    const int* __restrict__ rowptr, const int* __restrict__ csr_src,
    const float* __restrict__ b2, float* __restrict__ out, int N) {
    int wv = threadIdx.x >> 6;
    int lane = threadIdx.x & 63;
    int d = blockIdx.x * 4 + wv;
    if (d >= N) return;
    int beg = rowptr[d];
    int edeg = rowptr[d + 1] - beg;
    int tot = edeg + 1;
    float add = ad2[d];
    // phase 1: online max/sum (1 head), strided by 64
    float m = -1e30f, s = 0.f;
    for (int p = lane; p < tot; p += 64) {
        int sn = (p < edeg) ? csr_src[beg + p] : d;
        float e = as2[sn] + add;
        e = fmaxf(e, NEG_SLOPE * e);
        float nm = fmaxf(m, e);
        s = s * __expf(m - nm) + __expf(e - nm);
        m = nm;
    }
    #pragma unroll
    for (int mask = 1; mask < 64; mask <<= 1) {
        float om = __shfl_xor(m, mask);
        float os = __shfl_xor(s, mask);
        float nm = fmaxf(m, om);
        s = s * __expf(m - nm) + os * __expf(om - nm);
        m = nm;
    }
    float inv = 1.f / (s + 1e-16f);
    // phase 2: 4 edges/iter
    int q = lane & 15;
    int g = lane >> 4;
    float acc0 = 0.f, acc1 = 0.f, acc2 = 0.f, acc3 = 0.f;
    for (int p0 = 0; p0 < tot; p0 += 4) {
        int p = p0 + g;
        int sn = (p < edeg) ? csr_src[beg + p] : d;
        float w = 0.f;
        if (p < tot) {
            float e = as2[sn] + add;
            e = fmaxf(e, NEG_SLOPE * e);
            w = __expf(e - m);
        }
        const float4 hv = *reinterpret_cast<const float4*>(&h2[(size_t)sn * 64 + q * 4]);
        acc0 = fmaf(w, hv.x, acc0);
        acc1 = fmaf(w, hv.y, acc1);
        acc2 = fmaf(w, hv.z, acc2);
        acc3 = fmaf(w, hv.w, acc3);
    }
    #pragma unroll
    for (int mask = 16; mask < 64; mask <<= 1) {
        acc0 += __shfl_xor(acc0, mask);
        acc1 += __shfl_xor(acc1, mask);
        acc2 += __shfl_xor(acc2, mask);
        acc3 += __shfl_xor(acc3, mask);
    }
    // all lanes hold dims 4q..4q+3 (replicated over g groups)
    const float4 bv = *reinterpret_cast<const float4*>(&b2[q * 4]);
    float o0 = fmaf(acc0, inv, bv.x);
    float o1 = fmaf(acc1, inv, bv.y);
    float o2 = fmaf(acc2, inv, bv.z);
    float o3 = fmaf(acc3, inv, bv.w);
    // log_softmax over 64 dims: reduce within each 16-lane g-group (covers all q)
    float mx = fmaxf(fmaxf(o0, o1), fmaxf(o2, o3));
    #pragma unroll
    for (int mask = 1; mask < 16; mask <<= 1) mx = fmaxf(mx, __shfl_xor(mx, mask));
    float sm = __expf(o0 - mx) + __expf(o1 - mx) + __expf(o2 - mx) + __expf(o3 - mx);
    #pragma unroll
    for (int mask = 1; mask < 16; mask <<= 1) sm += __shfl_xor(sm, mask);
    float lse = mx + __logf(sm);
    if (lane < 16) {
        float4 o;
        o.x = o0 - lse; o.y = o1 - lse; o.z = o2 - lse; o.w = o3 - lse;
        *reinterpret_cast<float4*>(&out[(size_t)d * 64 + q * 4]) = o;
    }
}

// ---------------- launch ----------------

extern "C" void kernel_launch(void* const* d_in, const int* in_sizes, int n_in,
                              void* d_out, int out_size, void* d_ws, size_t ws_size,
                              hipStream_t stream) {
    const float* x      = (const float*)d_in[0];
    const int*   ei     = (const int*)d_in[1];
    const float* W1     = (const float*)d_in[2];
    const float* a_src1 = (const float*)d_in[3];
    const float* a_dst1 = (const float*)d_in[4];
    const float* b1     = (const float*)d_in[5];
    const float* W2     = (const float*)d_in[6];
    const float* a_src2 = (const float*)d_in[7];
    const float* a_dst2 = (const float*)d_in[8];
    const float* b2     = (const float*)d_in[9];

    int N = in_sizes[0] / 512;
    int E = in_sizes[1] / 2;
    const int* src = ei;
    const int* dst = ei + E;

    char* w = (char*)d_ws;
    size_t off = 0;
    auto alloc = [&](size_t bytes) -> void* {
        off = (off + 255) & ~(size_t)255;
        void* p = w + off;
        off += bytes;
        return p;
    };
    int* deg    = (int*)alloc((size_t)2 * N * sizeof(int));
    int* cursor = deg + N;
    int* rowptr = (int*)alloc((size_t)(N + 1) * sizeof(int));
    int* csr    = (int*)alloc((size_t)E * sizeof(int));
    float* h1   = (float*)alloc((size_t)N * 64 * sizeof(float));
    float* as1  = (float*)alloc((size_t)N * 8 * sizeof(float));
    float* ad1  = (float*)alloc((size_t)N * 8 * sizeof(float));
    float* helu = (float*)alloc((size_t)N * 64 * sizeof(float));
    float* h2  = h1;   // aliases (h1/as1/ad1 dead after attn1)
    float* as2 = as1;
    float* ad2 = ad1;

    zero_int_kernel<<<(2 * N + 255) / 256, 256, 0, stream>>>(deg, 2 * N);
    hist_kernel<<<(E + 255) / 256, 256, 0, stream>>>(dst, E, deg);
    scan_kernel<<<1, 1024, 0, stream>>>(deg, rowptr, N);
    scatter_kernel<<<(E + 255) / 256, 256, 0, stream>>>(src, dst, E, rowptr, cursor, csr);

    gemm1_kernel<<<(N + BM - 1) / BM, 256, 0, stream>>>(x, W1, h1, N);
    alphas1_kernel<<<(N * 8 + 255) / 256, 256, 0, stream>>>(h1, a_src1, a_dst1, as1, ad1, N);
    attn1_kernel<<<(N + 3) / 4, 256, 0, stream>>>(h1, as1, ad1, rowptr, csr, b1, helu, N);

    gemm2_kernel<<<2048, 256, 0, stream>>>(helu, W2, a_src2, a_dst2, h2, as2, ad2, N);
    attn2_kernel<<<(N + 3) / 4, 256, 0, stream>>>(h2, as2, ad2, rowptr, csr, b2, (float*)d_out, N);
}

// Round 3
// 872.659 us; speedup vs baseline: 1.5605x; 1.1456x over previous
//
#include <hip/hip_runtime.h>

#define NEG_SLOPE 0.2f

// bf16 helpers (RNE pack, cheap unpack)
__device__ inline unsigned f2bf(float f) {
    unsigned u = __float_as_uint(f);
    return (u + 0x7fffu + ((u >> 16) & 1u)) >> 16;
}
__device__ inline void bf2x4(uint2 u, float& f0, float& f1, float& f2, float& f3) {
    f0 = __uint_as_float(u.x << 16);
    f1 = __uint_as_float(u.x & 0xffff0000u);
    f2 = __uint_as_float(u.y << 16);
    f3 = __uint_as_float(u.y & 0xffff0000u);
}

// ---------------- CSR build ----------------

__global__ void zero_int_kernel(int* __restrict__ p, int n) {
    int i = blockIdx.x * blockDim.x + threadIdx.x;
    if (i < n) p[i] = 0;
}

__global__ void hist_kernel(const int* __restrict__ dst, int E, int* __restrict__ deg) {
    int i = blockIdx.x * blockDim.x + threadIdx.x;
    if (i < E) atomicAdd(&deg[dst[i]], 1);
}

__global__ __launch_bounds__(1024) void scan_kernel(const int* __restrict__ deg,
                                                    int* __restrict__ rowptr, int N) {
    __shared__ int sums[1024];
    int t = threadIdx.x;
    int chunk = (N + 1023) / 1024;
    int lo = t * chunk;
    int hi = min(lo + chunk, N);
    int s = 0;
    for (int i = lo; i < hi; ++i) s += deg[i];
    sums[t] = s;
    __syncthreads();
    for (int off = 1; off < 1024; off <<= 1) {
        int v = (t >= off) ? sums[t - off] : 0;
        __syncthreads();
        sums[t] += v;
        __syncthreads();
    }
    int run = sums[t] - s;  // exclusive prefix
    for (int i = lo; i < hi; ++i) { rowptr[i] = run; run += deg[i]; }
    if (hi == N) rowptr[N] = run;
}

__global__ void scatter_kernel(const int* __restrict__ src, const int* __restrict__ dst, int E,
                               const int* __restrict__ rowptr, int* __restrict__ cursor,
                               int* __restrict__ csr_src) {
    int i = blockIdx.x * blockDim.x + threadIdx.x;
    if (i < E) {
        int d = dst[i];
        int p = atomicAdd(&cursor[d], 1);
        csr_src[rowptr[d] + p] = src[i];
    }
}

// ---- GEMM1: hb1 = bf16(x @ W1), plus fused as1/ad1 epilogue ----

#define BM 64
#define BN 64
#define BK 32

__global__ __launch_bounds__(256) void gemm1_kernel(const float* __restrict__ x,
                                                    const float* __restrict__ W,
                                                    const float* __restrict__ a_src,
                                                    const float* __restrict__ a_dst,
                                                    unsigned short* __restrict__ hb1,
                                                    float* __restrict__ as1,
                                                    float* __restrict__ ad1, int N) {
    __shared__ float As[BK][BM + 4];
    __shared__ float Bs[BK][BN + 4];
    int tid = threadIdx.x;
    int row0 = blockIdx.x * BM;
    int ty = tid >> 4;          // 0..15
    int tx = tid & 15;          // 0..15
    float aswr[4], adwr[4];
    #pragma unroll
    for (int j = 0; j < 4; ++j) { aswr[j] = a_src[tx * 4 + j]; adwr[j] = a_dst[tx * 4 + j]; }
    float acc[4][4] = {};
    for (int kt = 0; kt < 512; kt += BK) {
        int r = tid >> 3;               // 0..31
        int kk = (tid & 7) * 4;         // 0..28
        #pragma unroll
        for (int rr = 0; rr < BM; rr += 32) {
            int grow = row0 + r + rr;
            float4 v = make_float4(0.f, 0.f, 0.f, 0.f);
            if (grow < N)
                v = *reinterpret_cast<const float4*>(&x[(size_t)grow * 512 + kt + kk]);
            As[kk + 0][r + rr] = v.x;
            As[kk + 1][r + rr] = v.y;
            As[kk + 2][r + rr] = v.z;
            As[kk + 3][r + rr] = v.w;
        }
        int br = tid >> 4;              // 0..15
        int bc = (tid & 15) * 4;        // 0..60
        #pragma unroll
        for (int rr = 0; rr < BK; rr += 16) {
            float4 v = *reinterpret_cast<const float4*>(&W[(size_t)(kt + br + rr) * 64 + bc]);
            Bs[br + rr][bc + 0] = v.x;
            Bs[br + rr][bc + 1] = v.y;
            Bs[br + rr][bc + 2] = v.z;
            Bs[br + rr][bc + 3] = v.w;
        }
        __syncthreads();
        #pragma unroll
        for (int k = 0; k < BK; ++k) {
            float a[4], b[4];
            #pragma unroll
            for (int i = 0; i < 4; ++i) a[i] = As[k][ty * 4 + i];
            #pragma unroll
            for (int j = 0; j < 4; ++j) b[j] = Bs[k][tx * 4 + j];
            #pragma unroll
            for (int i = 0; i < 4; ++i)
                #pragma unroll
                for (int j = 0; j < 4; ++j) acc[i][j] += a[i] * b[j];
        }
        __syncthreads();
    }
    uint2* hb2p = reinterpret_cast<uint2*>(hb1);
    #pragma unroll
    for (int i = 0; i < 4; ++i) {
        int grow = row0 + ty * 4 + i;
        if (grow < N) {
            uint2 o;
            o.x = f2bf(acc[i][0]) | (f2bf(acc[i][1]) << 16);
            o.y = f2bf(acc[i][2]) | (f2bf(acc[i][3]) << 16);
            hb2p[(size_t)grow * 16 + tx] = o;
            // alpha partials: head = tx>>1, pair-reduce with tx^1 (lane^1)
            float sa = acc[i][0] * aswr[0] + acc[i][1] * aswr[1] +
                       acc[i][2] * aswr[2] + acc[i][3] * aswr[3];
            float sd = acc[i][0] * adwr[0] + acc[i][1] * adwr[1] +
                       acc[i][2] * adwr[2] + acc[i][3] * adwr[3];
            sa += __shfl_xor(sa, 1);
            sd += __shfl_xor(sd, 1);
            if ((tx & 1) == 0) {
                as1[grow * 8 + (tx >> 1)] = sa;
                ad1[grow * 8 + (tx >> 1)] = sd;
            }
        }
    }
}

// ---- layer-1 attention: fused online softmax + aggregation (1 wave/dst, 4 edges/iter) ----

__global__ __launch_bounds__(256) void attn1_kernel(
    const unsigned short* __restrict__ hb1, const float* __restrict__ as1,
    const float* __restrict__ ad1, const int* __restrict__ rowptr,
    const int* __restrict__ csr_src, const float* __restrict__ b1,
    float* __restrict__ helu, int N) {
    int wv = threadIdx.x >> 6;
    int lane = threadIdx.x & 63;
    int d = blockIdx.x * 4 + wv;
    if (d >= N) return;
    int beg = rowptr[d];
    int edeg = rowptr[d + 1] - beg;
    int tot = edeg + 1;  // + virtual self loop (src = d)
    int q = lane & 15, g = lane >> 4, hh = q >> 1;
    float adh = ad1[d * 8 + hh];
    const uint2* hb = reinterpret_cast<const uint2*>(hb1);
    float m = -1e30f, s = 0.f, a0 = 0.f, a1 = 0.f, a2 = 0.f, a3 = 0.f;
    for (int p0 = 0; p0 < tot; p0 += 4) {
        int p = p0 + g;
        bool valid = p < tot;
        int sn = (p < edeg) ? csr_src[beg + p] : d;
        float e = as1[sn * 8 + hh] + adh;
        e = fmaxf(e, NEG_SLOPE * e);
        float nm = valid ? fmaxf(m, e) : m;
        float sc = __expf(m - nm);
        float w = valid ? __expf(e - nm) : 0.f;
        uint2 u = hb[(size_t)sn * 16 + q];
        float f0, f1, f2, f3;
        bf2x4(u, f0, f1, f2, f3);
        s = fmaf(s, sc, w);
        a0 = fmaf(a0, sc, w * f0);
        a1 = fmaf(a1, sc, w * f1);
        a2 = fmaf(a2, sc, w * f2);
        a3 = fmaf(a3, sc, w * f3);
        m = nm;
    }
    #pragma unroll
    for (int mask = 16; mask < 64; mask <<= 1) {
        float om = __shfl_xor(m, mask), os = __shfl_xor(s, mask);
        float o0 = __shfl_xor(a0, mask), o1 = __shfl_xor(a1, mask);
        float o2 = __shfl_xor(a2, mask), o3 = __shfl_xor(a3, mask);
        float nm = fmaxf(m, om);
        float x1 = __expf(m - nm), x2 = __expf(om - nm);
        s = s * x1 + os * x2;
        a0 = a0 * x1 + o0 * x2;
        a1 = a1 * x1 + o1 * x2;
        a2 = a2 * x1 + o2 * x2;
        a3 = a3 * x1 + o3 * x2;
        m = nm;
    }
    if (lane < 16) {
        float inv = 1.f / (s + 1e-16f);
        const float4 bv = *reinterpret_cast<const float4*>(&b1[q * 4]);
        float4 o;
        o.x = fmaf(a0, inv, bv.x);
        o.y = fmaf(a1, inv, bv.y);
        o.z = fmaf(a2, inv, bv.z);
        o.w = fmaf(a3, inv, bv.w);
        o.x = (o.x > 0.f) ? o.x : (__expf(o.x) - 1.f);
        o.y = (o.y > 0.f) ? o.y : (__expf(o.y) - 1.f);
        o.z = (o.z > 0.f) ? o.z : (__expf(o.z) - 1.f);
        o.w = (o.w > 0.f) ? o.w : (__expf(o.w) - 1.f);
        *reinterpret_cast<float4*>(&helu[(size_t)d * 64 + q * 4]) = o;
    }
}

// ---- GEMM2 (64x64) + alpha2, one wave per row; bf16 h2 out ----

__global__ __launch_bounds__(256) void gemm2_kernel(
    const float* __restrict__ helu, const float* __restrict__ W2,
    const float* __restrict__ a_src2, const float* __restrict__ a_dst2,
    unsigned short* __restrict__ hb2, float* __restrict__ as2, float* __restrict__ ad2, int N) {
    __shared__ float Ws[64 * 64];
    __shared__ float asw[64], adw[64];
    int tid = threadIdx.x;
    for (int i = tid; i < 64 * 64; i += 256) Ws[i] = W2[i];
    if (tid < 64) { asw[tid] = a_src2[tid]; adw[tid] = a_dst2[tid]; }
    __syncthreads();
    int lane = tid & 63, wv = tid >> 6;
    int stride = gridDim.x * 4;
    for (int row = blockIdx.x * 4 + wv; row < N; row += stride) {
        float hv = helu[(size_t)row * 64 + lane];
        float acc = 0.f;
        #pragma unroll
        for (int k = 0; k < 64; ++k) {
            float v = __shfl(hv, k);
            acc += v * Ws[k * 64 + lane];
        }
        hb2[(size_t)row * 64 + lane] = (unsigned short)f2bf(acc);
        float pa = acc * asw[lane];
        float pb = acc * adw[lane];
        #pragma unroll
        for (int mask = 1; mask < 64; mask <<= 1) {
            pa += __shfl_xor(pa, mask);
            pb += __shfl_xor(pb, mask);
        }
        if (lane == 0) { as2[row] = pa; ad2[row] = pb; }
    }
}

// ---- layer-2 attention + log_softmax (fused online softmax, 4 edges/iter) ----

__global__ __launch_bounds__(256) void attn2_kernel(
    const unsigned short* __restrict__ hb2, const float* __restrict__ as2,
    const float* __restrict__ ad2, const int* __restrict__ rowptr,
    const int* __restrict__ csr_src, const float* __restrict__ b2,
    float* __restrict__ out, int N) {
    int wv = threadIdx.x >> 6;
    int lane = threadIdx.x & 63;
    int d = blockIdx.x * 4 + wv;
    if (d >= N) return;
    int beg = rowptr[d];
    int edeg = rowptr[d + 1] - beg;
    int tot = edeg + 1;
    int q = lane & 15, g = lane >> 4;
    float add = ad2[d];
    const uint2* hb = reinterpret_cast<const uint2*>(hb2);
    float m = -1e30f, s = 0.f, a0 = 0.f, a1 = 0.f, a2 = 0.f, a3 = 0.f;
    for (int p0 = 0; p0 < tot; p0 += 4) {
        int p = p0 + g;
        bool valid = p < tot;
        int sn = (p < edeg) ? csr_src[beg + p] : d;
        float e = as2[sn] + add;
        e = fmaxf(e, NEG_SLOPE * e);
        float nm = valid ? fmaxf(m, e) : m;
        float sc = __expf(m - nm);
        float w = valid ? __expf(e - nm) : 0.f;
        uint2 u = hb[(size_t)sn * 16 + q];
        float f0, f1, f2, f3;
        bf2x4(u, f0, f1, f2, f3);
        s = fmaf(s, sc, w);
        a0 = fmaf(a0, sc, w * f0);
        a1 = fmaf(a1, sc, w * f1);
        a2 = fmaf(a2, sc, w * f2);
        a3 = fmaf(a3, sc, w * f3);
        m = nm;
    }
    #pragma unroll
    for (int mask = 16; mask < 64; mask <<= 1) {
        float om = __shfl_xor(m, mask), os = __shfl_xor(s, mask);
        float o0 = __shfl_xor(a0, mask), o1 = __shfl_xor(a1, mask);
        float o2 = __shfl_xor(a2, mask), o3 = __shfl_xor(a3, mask);
        float nm = fmaxf(m, om);
        float x1 = __expf(m - nm), x2 = __expf(om - nm);
        s = s * x1 + os * x2;
        a0 = a0 * x1 + o0 * x2;
        a1 = a1 * x1 + o1 * x2;
        a2 = a2 * x1 + o2 * x2;
        a3 = a3 * x1 + o3 * x2;
        m = nm;
    }
    float inv = 1.f / (s + 1e-16f);
    const float4 bv = *reinterpret_cast<const float4*>(&b2[q * 4]);
    float o0 = fmaf(a0, inv, bv.x);
    float o1 = fmaf(a1, inv, bv.y);
    float o2 = fmaf(a2, inv, bv.z);
    float o3 = fmaf(a3, inv, bv.w);
    // log_softmax over 64 dims: reduce within each 16-lane g-group (covers all q)
    float mx = fmaxf(fmaxf(o0, o1), fmaxf(o2, o3));
    #pragma unroll
    for (int mask = 1; mask < 16; mask <<= 1) mx = fmaxf(mx, __shfl_xor(mx, mask));
    float sm = __expf(o0 - mx) + __expf(o1 - mx) + __expf(o2 - mx) + __expf(o3 - mx);
    #pragma unroll
    for (int mask = 1; mask < 16; mask <<= 1) sm += __shfl_xor(sm, mask);
    float lse = mx + __logf(sm);
    if (lane < 16) {
        float4 o;
        o.x = o0 - lse; o.y = o1 - lse; o.z = o2 - lse; o.w = o3 - lse;
        *reinterpret_cast<float4*>(&out[(size_t)d * 64 + q * 4]) = o;
    }
}

// ---------------- launch ----------------

extern "C" void kernel_launch(void* const* d_in, const int* in_sizes, int n_in,
                              void* d_out, int out_size, void* d_ws, size_t ws_size,
                              hipStream_t stream) {
    const float* x      = (const float*)d_in[0];
    const int*   ei     = (const int*)d_in[1];
    const float* W1     = (const float*)d_in[2];
    const float* a_src1 = (const float*)d_in[3];
    const float* a_dst1 = (const float*)d_in[4];
    const float* b1     = (const float*)d_in[5];
    const float* W2     = (const float*)d_in[6];
    const float* a_src2 = (const float*)d_in[7];
    const float* a_dst2 = (const float*)d_in[8];
    const float* b2     = (const float*)d_in[9];

    int N = in_sizes[0] / 512;
    int E = in_sizes[1] / 2;
    const int* src = ei;
    const int* dst = ei + E;

    char* w = (char*)d_ws;
    size_t off = 0;
    auto alloc = [&](size_t bytes) -> void* {
        off = (off + 255) & ~(size_t)255;
        void* p = w + off;
        off += bytes;
        return p;
    };
    int* deg    = (int*)alloc((size_t)2 * N * sizeof(int));
    int* cursor = deg + N;
    int* rowptr = (int*)alloc((size_t)(N + 1) * sizeof(int));
    int* csr    = (int*)alloc((size_t)E * sizeof(int));
    unsigned short* hb1 = (unsigned short*)alloc((size_t)N * 64 * sizeof(unsigned short));
    float* as1  = (float*)alloc((size_t)N * 8 * sizeof(float));
    float* ad1  = (float*)alloc((size_t)N * 8 * sizeof(float));
    float* helu = (float*)alloc((size_t)N * 64 * sizeof(float));
    unsigned short* hb2 = hb1;   // aliases: hb1/as1/ad1 dead after attn1
    float* as2 = as1;
    float* ad2 = ad1;

    zero_int_kernel<<<(2 * N + 255) / 256, 256, 0, stream>>>(deg, 2 * N);
    hist_kernel<<<(E + 255) / 256, 256, 0, stream>>>(dst, E, deg);
    scan_kernel<<<1, 1024, 0, stream>>>(deg, rowptr, N);
    scatter_kernel<<<(E + 255) / 256, 256, 0, stream>>>(src, dst, E, rowptr, cursor, csr);

    gemm1_kernel<<<(N + BM - 1) / BM, 256, 0, stream>>>(x, W1, a_src1, a_dst1, hb1, as1, ad1, N);
    attn1_kernel<<<(N + 3) / 4, 256, 0, stream>>>(hb1, as1, ad1, rowptr, csr, b1, helu, N);

    gemm2_kernel<<<2048, 256, 0, stream>>>(helu, W2, a_src2, a_dst2, hb2, as2, ad2, N);
    attn2_kernel<<<(N + 3) / 4, 256, 0, stream>>>(hb2, as2, ad2, rowptr, csr, b2, (float*)d_out, N);
}

// Round 4
// 721.363 us; speedup vs baseline: 1.8878x; 1.2097x over previous
//
#include <hip/hip_runtime.h>

#define NEG_SLOPE 0.2f

// bf16 helpers (RNE pack, cheap unpack)
__device__ inline unsigned f2bf(float f) {
    unsigned u = __float_as_uint(f);
    return (u + 0x7fffu + ((u >> 16) & 1u)) >> 16;
}
__device__ inline void bf2x4(uint2 u, float& f0, float& f1, float& f2, float& f3) {
    f0 = __uint_as_float(u.x << 16);
    f1 = __uint_as_float(u.x & 0xffff0000u);
    f2 = __uint_as_float(u.y << 16);
    f3 = __uint_as_float(u.y & 0xffff0000u);
}

// ---------------- CSR build ----------------

__global__ void zero_int_kernel(int* __restrict__ p, int n) {
    int i = blockIdx.x * blockDim.x + threadIdx.x;
    if (i < n) p[i] = 0;
}

__global__ void hist_kernel(const int* __restrict__ dst, int E, int* __restrict__ deg) {
    int i = blockIdx.x * blockDim.x + threadIdx.x;
    if (i < E) atomicAdd(&deg[dst[i]], 1);
}

// ---- multi-block scan: 1024 elements per 256-thread block ----
#define SCAN_PER 1024

__global__ __launch_bounds__(256) void scan_reduce_kernel(const int* __restrict__ deg,
                                                          int* __restrict__ bsum, int N) {
    int t = threadIdx.x;
    int base = blockIdx.x * SCAN_PER + t * 4;
    int4 v = make_int4(0, 0, 0, 0);
    if (base + 3 < N) v = *reinterpret_cast<const int4*>(&deg[base]);
    else {
        if (base + 0 < N) v.x = deg[base + 0];
        if (base + 1 < N) v.y = deg[base + 1];
        if (base + 2 < N) v.z = deg[base + 2];
    }
    int s = v.x + v.y + v.z + v.w;
    #pragma unroll
    for (int m = 1; m < 64; m <<= 1) s += __shfl_xor(s, m);
    __shared__ int ws[4];
    if ((t & 63) == 0) ws[t >> 6] = s;
    __syncthreads();
    if (t == 0) bsum[blockIdx.x] = ws[0] + ws[1] + ws[2] + ws[3];
}

// single block: exclusive-scan bsum[nb] in place (nb <= 256); writes rowptr[N]=total
__global__ __launch_bounds__(256) void scan_bsum_kernel(int* __restrict__ bsum, int nb,
                                                        int* __restrict__ rowptr, int N) {
    int t = threadIdx.x;
    int v = (t < nb) ? bsum[t] : 0;
    int s = v;
    #pragma unroll
    for (int d = 1; d < 64; d <<= 1) {
        int o = __shfl_up(s, d);
        if ((t & 63) >= d) s += o;
    }
    __shared__ int ws[4];
    if ((t & 63) == 63) ws[t >> 6] = s;
    __syncthreads();
    int woff = 0;
    int wid = t >> 6;
    for (int w = 0; w < 4; ++w) woff += (w < wid) ? ws[w] : 0;
    int excl = s - v + woff;
    if (t < nb) bsum[t] = excl;
    if (t == 255) rowptr[N] = excl + v;  // grand total
}

__global__ __launch_bounds__(256) void scan_write_kernel(const int* __restrict__ deg,
                                                         const int* __restrict__ bsum,
                                                         int* __restrict__ rowptr, int N) {
    int t = threadIdx.x;
    int base = blockIdx.x * SCAN_PER + t * 4;
    int4 v = make_int4(0, 0, 0, 0);
    if (base + 3 < N) v = *reinterpret_cast<const int4*>(&deg[base]);
    else {
        if (base + 0 < N) v.x = deg[base + 0];
        if (base + 1 < N) v.y = deg[base + 1];
        if (base + 2 < N) v.z = deg[base + 2];
    }
    int s = v.x + v.y + v.z + v.w;
    int incl = s;
    #pragma unroll
    for (int d = 1; d < 64; d <<= 1) {
        int o = __shfl_up(incl, d);
        if ((t & 63) >= d) incl += o;
    }
    __shared__ int ws[4];
    if ((t & 63) == 63) ws[t >> 6] = incl;
    __syncthreads();
    int wid = t >> 6;
    int woff = 0;
    for (int w = 0; w < 4; ++w) woff += (w < wid) ? ws[w] : 0;
    int excl = incl - s + woff + bsum[blockIdx.x];
    if (base + 0 < N) rowptr[base + 0] = excl;
    if (base + 1 < N) rowptr[base + 1] = excl + v.x;
    if (base + 2 < N) rowptr[base + 2] = excl + v.x + v.y;
    if (base + 3 < N) rowptr[base + 3] = excl + v.x + v.y + v.z;
}

__global__ void scatter_kernel(const int* __restrict__ src, const int* __restrict__ dst, int E,
                               const int* __restrict__ rowptr, int* __restrict__ cursor,
                               int* __restrict__ csr_src) {
    int i = blockIdx.x * blockDim.x + threadIdx.x;
    if (i < E) {
        int d = dst[i];
        int p = atomicAdd(&cursor[d], 1);
        csr_src[rowptr[d] + p] = src[i];
    }
}

// ---- GEMM1: hb1 = bf16(x @ W1), plus fused as1/ad1 epilogue ----

#define BM 64
#define BN 64
#define BK 32

__global__ __launch_bounds__(256) void gemm1_kernel(const float* __restrict__ x,
                                                    const float* __restrict__ W,
                                                    const float* __restrict__ a_src,
                                                    const float* __restrict__ a_dst,
                                                    unsigned short* __restrict__ hb1,
                                                    float* __restrict__ as1,
                                                    float* __restrict__ ad1, int N) {
    __shared__ float As[BK][BM + 4];
    __shared__ float Bs[BK][BN + 4];
    int tid = threadIdx.x;
    int row0 = blockIdx.x * BM;
    int ty = tid >> 4;          // 0..15
    int tx = tid & 15;          // 0..15
    float aswr[4], adwr[4];
    #pragma unroll
    for (int j = 0; j < 4; ++j) { aswr[j] = a_src[tx * 4 + j]; adwr[j] = a_dst[tx * 4 + j]; }
    float acc[4][4] = {};
    for (int kt = 0; kt < 512; kt += BK) {
        int r = tid >> 3;               // 0..31
        int kk = (tid & 7) * 4;         // 0..28
        #pragma unroll
        for (int rr = 0; rr < BM; rr += 32) {
            int grow = row0 + r + rr;
            float4 v = make_float4(0.f, 0.f, 0.f, 0.f);
            if (grow < N)
                v = *reinterpret_cast<const float4*>(&x[(size_t)grow * 512 + kt + kk]);
            As[kk + 0][r + rr] = v.x;
            As[kk + 1][r + rr] = v.y;
            As[kk + 2][r + rr] = v.z;
            As[kk + 3][r + rr] = v.w;
        }
        int br = tid >> 4;              // 0..15
        int bc = (tid & 15) * 4;        // 0..60
        #pragma unroll
        for (int rr = 0; rr < BK; rr += 16) {
            float4 v = *reinterpret_cast<const float4*>(&W[(size_t)(kt + br + rr) * 64 + bc]);
            Bs[br + rr][bc + 0] = v.x;
            Bs[br + rr][bc + 1] = v.y;
            Bs[br + rr][bc + 2] = v.z;
            Bs[br + rr][bc + 3] = v.w;
        }
        __syncthreads();
        #pragma unroll
        for (int k = 0; k < BK; ++k) {
            float a[4], b[4];
            #pragma unroll
            for (int i = 0; i < 4; ++i) a[i] = As[k][ty * 4 + i];
            #pragma unroll
            for (int j = 0; j < 4; ++j) b[j] = Bs[k][tx * 4 + j];
            #pragma unroll
            for (int i = 0; i < 4; ++i)
                #pragma unroll
                for (int j = 0; j < 4; ++j) acc[i][j] += a[i] * b[j];
        }
        __syncthreads();
    }
    uint2* hb2p = reinterpret_cast<uint2*>(hb1);
    #pragma unroll
    for (int i = 0; i < 4; ++i) {
        int grow = row0 + ty * 4 + i;
        if (grow < N) {
            uint2 o;
            o.x = f2bf(acc[i][0]) | (f2bf(acc[i][1]) << 16);
            o.y = f2bf(acc[i][2]) | (f2bf(acc[i][3]) << 16);
            hb2p[(size_t)grow * 16 + tx] = o;
            float sa = acc[i][0] * aswr[0] + acc[i][1] * aswr[1] +
                       acc[i][2] * aswr[2] + acc[i][3] * aswr[3];
            float sd = acc[i][0] * adwr[0] + acc[i][1] * adwr[1] +
                       acc[i][2] * adwr[2] + acc[i][3] * adwr[3];
            sa += __shfl_xor(sa, 1);
            sd += __shfl_xor(sd, 1);
            if ((tx & 1) == 0) {
                as1[grow * 8 + (tx >> 1)] = sa;
                ad1[grow * 8 + (tx >> 1)] = sd;
            }
        }
    }
}

// ---- layer-1 attention: fused online softmax + aggregation (1 wave/dst, 4 edges/iter) ----

__global__ __launch_bounds__(256) void attn1_kernel(
    const unsigned short* __restrict__ hb1, const float* __restrict__ as1,
    const float* __restrict__ ad1, const int* __restrict__ rowptr,
    const int* __restrict__ csr_src, const float* __restrict__ b1,
    float* __restrict__ helu, int N) {
    int wv = threadIdx.x >> 6;
    int lane = threadIdx.x & 63;
    int d = blockIdx.x * 4 + wv;
    if (d >= N) return;
    int beg = rowptr[d];
    int edeg = rowptr[d + 1] - beg;
    int tot = edeg + 1;  // + virtual self loop (src = d)
    int q = lane & 15, g = lane >> 4, hh = q >> 1;
    float adh = ad1[d * 8 + hh];
    const uint2* hb = reinterpret_cast<const uint2*>(hb1);
    float m = -1e30f, s = 0.f, a0 = 0.f, a1 = 0.f, a2 = 0.f, a3 = 0.f;
    for (int p0 = 0; p0 < tot; p0 += 4) {
        int p = p0 + g;
        bool valid = p < tot;
        int sn = (p < edeg) ? csr_src[beg + p] : d;
        float e = as1[sn * 8 + hh] + adh;
        e = fmaxf(e, NEG_SLOPE * e);
        float nm = valid ? fmaxf(m, e) : m;
        float sc = __expf(m - nm);
        float w = valid ? __expf(e - nm) : 0.f;
        uint2 u = hb[(size_t)sn * 16 + q];
        float f0, f1, f2, f3;
        bf2x4(u, f0, f1, f2, f3);
        s = fmaf(s, sc, w);
        a0 = fmaf(a0, sc, w * f0);
        a1 = fmaf(a1, sc, w * f1);
        a2 = fmaf(a2, sc, w * f2);
        a3 = fmaf(a3, sc, w * f3);
        m = nm;
    }
    #pragma unroll
    for (int mask = 16; mask < 64; mask <<= 1) {
        float om = __shfl_xor(m, mask), os = __shfl_xor(s, mask);
        float o0 = __shfl_xor(a0, mask), o1 = __shfl_xor(a1, mask);
        float o2 = __shfl_xor(a2, mask), o3 = __shfl_xor(a3, mask);
        float nm = fmaxf(m, om);
        float x1 = __expf(m - nm), x2 = __expf(om - nm);
        s = s * x1 + os * x2;
        a0 = a0 * x1 + o0 * x2;
        a1 = a1 * x1 + o1 * x2;
        a2 = a2 * x1 + o2 * x2;
        a3 = a3 * x1 + o3 * x2;
        m = nm;
    }
    if (lane < 16) {
        float inv = 1.f / (s + 1e-16f);
        const float4 bv = *reinterpret_cast<const float4*>(&b1[q * 4]);
        float4 o;
        o.x = fmaf(a0, inv, bv.x);
        o.y = fmaf(a1, inv, bv.y);
        o.z = fmaf(a2, inv, bv.z);
        o.w = fmaf(a3, inv, bv.w);
        o.x = (o.x > 0.f) ? o.x : (__expf(o.x) - 1.f);
        o.y = (o.y > 0.f) ? o.y : (__expf(o.y) - 1.f);
        o.z = (o.z > 0.f) ? o.z : (__expf(o.z) - 1.f);
        o.w = (o.w > 0.f) ? o.w : (__expf(o.w) - 1.f);
        *reinterpret_cast<float4*>(&helu[(size_t)d * 64 + q * 4]) = o;
    }
}

// ---- GEMM2 (64x64) + alpha2, one wave per row; bf16 h2 out ----

__global__ __launch_bounds__(256) void gemm2_kernel(
    const float* __restrict__ helu, const float* __restrict__ W2,
    const float* __restrict__ a_src2, const float* __restrict__ a_dst2,
    unsigned short* __restrict__ hb2, float* __restrict__ as2, float* __restrict__ ad2, int N) {
    __shared__ float Ws[64 * 64];
    __shared__ float asw[64], adw[64];
    int tid = threadIdx.x;
    for (int i = tid; i < 64 * 64; i += 256) Ws[i] = W2[i];
    if (tid < 64) { asw[tid] = a_src2[tid]; adw[tid] = a_dst2[tid]; }
    __syncthreads();
    int lane = tid & 63, wv = tid >> 6;
    int stride = gridDim.x * 4;
    for (int row = blockIdx.x * 4 + wv; row < N; row += stride) {
        float hv = helu[(size_t)row * 64 + lane];
        float acc = 0.f;
        #pragma unroll
        for (int k = 0; k < 64; ++k) {
            float v = __shfl(hv, k);
            acc += v * Ws[k * 64 + lane];
        }
        hb2[(size_t)row * 64 + lane] = (unsigned short)f2bf(acc);
        float pa = acc * asw[lane];
        float pb = acc * adw[lane];
        #pragma unroll
        for (int mask = 1; mask < 64; mask <<= 1) {
            pa += __shfl_xor(pa, mask);
            pb += __shfl_xor(pb, mask);
        }
        if (lane == 0) { as2[row] = pa; ad2[row] = pb; }
    }
}

// ---- layer-2 attention + log_softmax (fused online softmax, 4 edges/iter) ----

__global__ __launch_bounds__(256) void attn2_kernel(
    const unsigned short* __restrict__ hb2, const float* __restrict__ as2,
    const float* __restrict__ ad2, const int* __restrict__ rowptr,
    const int* __restrict__ csr_src, const float* __restrict__ b2,
    float* __restrict__ out, int N) {
    int wv = threadIdx.x >> 6;
    int lane = threadIdx.x & 63;
    int d = blockIdx.x * 4 + wv;
    if (d >= N) return;
    int beg = rowptr[d];
    int edeg = rowptr[d + 1] - beg;
    int tot = edeg + 1;
    int q = lane & 15, g = lane >> 4;
    float add = ad2[d];
    const uint2* hb = reinterpret_cast<const uint2*>(hb2);
    float m = -1e30f, s = 0.f, a0 = 0.f, a1 = 0.f, a2 = 0.f, a3 = 0.f;
    for (int p0 = 0; p0 < tot; p0 += 4) {
        int p = p0 + g;
        bool valid = p < tot;
        int sn = (p < edeg) ? csr_src[beg + p] : d;
        float e = as2[sn] + add;
        e = fmaxf(e, NEG_SLOPE * e);
        float nm = valid ? fmaxf(m, e) : m;
        float sc = __expf(m - nm);
        float w = valid ? __expf(e - nm) : 0.f;
        uint2 u = hb[(size_t)sn * 16 + q];
        float f0, f1, f2, f3;
        bf2x4(u, f0, f1, f2, f3);
        s = fmaf(s, sc, w);
        a0 = fmaf(a0, sc, w * f0);
        a1 = fmaf(a1, sc, w * f1);
        a2 = fmaf(a2, sc, w * f2);
        a3 = fmaf(a3, sc, w * f3);
        m = nm;
    }
    #pragma unroll
    for (int mask = 16; mask < 64; mask <<= 1) {
        float om = __shfl_xor(m, mask), os = __shfl_xor(s, mask);
        float o0 = __shfl_xor(a0, mask), o1 = __shfl_xor(a1, mask);
        float o2 = __shfl_xor(a2, mask), o3 = __shfl_xor(a3, mask);
        float nm = fmaxf(m, om);
        float x1 = __expf(m - nm), x2 = __expf(om - nm);
        s = s * x1 + os * x2;
        a0 = a0 * x1 + o0 * x2;
        a1 = a1 * x1 + o1 * x2;
        a2 = a2 * x1 + o2 * x2;
        a3 = a3 * x1 + o3 * x2;
        m = nm;
    }
    float inv = 1.f / (s + 1e-16f);
    const float4 bv = *reinterpret_cast<const float4*>(&b2[q * 4]);
    float o0 = fmaf(a0, inv, bv.x);
    float o1 = fmaf(a1, inv, bv.y);
    float o2 = fmaf(a2, inv, bv.z);
    float o3 = fmaf(a3, inv, bv.w);
    float mx = fmaxf(fmaxf(o0, o1), fmaxf(o2, o3));
    #pragma unroll
    for (int mask = 1; mask < 16; mask <<= 1) mx = fmaxf(mx, __shfl_xor(mx, mask));
    float sm = __expf(o0 - mx) + __expf(o1 - mx) + __expf(o2 - mx) + __expf(o3 - mx);
    #pragma unroll
    for (int mask = 1; mask < 16; mask <<= 1) sm += __shfl_xor(sm, mask);
    float lse = mx + __logf(sm);
    if (lane < 16) {
        float4 o;
        o.x = o0 - lse; o.y = o1 - lse; o.z = o2 - lse; o.w = o3 - lse;
        *reinterpret_cast<float4*>(&out[(size_t)d * 64 + q * 4]) = o;
    }
}

// ---------------- launch ----------------

extern "C" void kernel_launch(void* const* d_in, const int* in_sizes, int n_in,
                              void* d_out, int out_size, void* d_ws, size_t ws_size,
                              hipStream_t stream) {
    const float* x      = (const float*)d_in[0];
    const int*   ei     = (const int*)d_in[1];
    const float* W1     = (const float*)d_in[2];
    const float* a_src1 = (const float*)d_in[3];
    const float* a_dst1 = (const float*)d_in[4];
    const float* b1     = (const float*)d_in[5];
    const float* W2     = (const float*)d_in[6];
    const float* a_src2 = (const float*)d_in[7];
    const float* a_dst2 = (const float*)d_in[8];
    const float* b2     = (const float*)d_in[9];

    int N = in_sizes[0] / 512;
    int E = in_sizes[1] / 2;
    const int* src = ei;
    const int* dst = ei + E;

    char* w = (char*)d_ws;
    size_t off = 0;
    auto alloc = [&](size_t bytes) -> void* {
        off = (off + 255) & ~(size_t)255;
        void* p = w + off;
        off += bytes;
        return p;
    };
    int* deg    = (int*)alloc((size_t)2 * N * sizeof(int));
    int* cursor = deg + N;
    int* rowptr = (int*)alloc((size_t)(N + 1) * sizeof(int));
    int nb = (N + SCAN_PER - 1) / SCAN_PER;
    int* bsum   = (int*)alloc((size_t)nb * sizeof(int));
    int* csr    = (int*)alloc((size_t)E * sizeof(int));
    unsigned short* hb1 = (unsigned short*)alloc((size_t)N * 64 * sizeof(unsigned short));
    float* as1  = (float*)alloc((size_t)N * 8 * sizeof(float));
    float* ad1  = (float*)alloc((size_t)N * 8 * sizeof(float));
    float* helu = (float*)alloc((size_t)N * 64 * sizeof(float));
    unsigned short* hb2 = hb1;   // aliases: hb1/as1/ad1 dead after attn1
    float* as2 = as1;
    float* ad2 = ad1;

    zero_int_kernel<<<(2 * N + 255) / 256, 256, 0, stream>>>(deg, 2 * N);
    hist_kernel<<<(E + 255) / 256, 256, 0, stream>>>(dst, E, deg);
    scan_reduce_kernel<<<nb, 256, 0, stream>>>(deg, bsum, N);
    scan_bsum_kernel<<<1, 256, 0, stream>>>(bsum, nb, rowptr, N);
    scan_write_kernel<<<nb, 256, 0, stream>>>(deg, bsum, rowptr, N);
    scatter_kernel<<<(E + 255) / 256, 256, 0, stream>>>(src, dst, E, rowptr, cursor, csr);

    gemm1_kernel<<<(N + BM - 1) / BM, 256, 0, stream>>>(x, W1, a_src1, a_dst1, hb1, as1, ad1, N);
    attn1_kernel<<<(N + 3) / 4, 256, 0, stream>>>(hb1, as1, ad1, rowptr, csr, b1, helu, N);

    gemm2_kernel<<<2048, 256, 0, stream>>>(helu, W2, a_src2, a_dst2, hb2, as2, ad2, N);
    attn2_kernel<<<(N + 3) / 4, 256, 0, stream>>>(hb2, as2, ad2, rowptr, csr, b2, (float*)d_out, N);
}

// Round 5
// 701.343 us; speedup vs baseline: 1.9416x; 1.0285x over previous
//
#include <hip/hip_runtime.h>

#define NEG_SLOPE 0.2f
#define NB_SHIFT 8          // bucket = dst >> 8 (256-node windows)

// bf16 helpers (RNE pack, cheap unpack)
__device__ inline unsigned f2bf(float f) {
    unsigned u = __float_as_uint(f);
    return (u + 0x7fffu + ((u >> 16) & 1u)) >> 16;
}
__device__ inline void bf2x4(uint2 u, float& f0, float& f1, float& f2, float& f3) {
    f0 = __uint_as_float(u.x << 16);
    f1 = __uint_as_float(u.x & 0xffff0000u);
    f2 = __uint_as_float(u.y << 16);
    f3 = __uint_as_float(u.y & 0xffff0000u);
}

// ---------------- CSR build ----------------

__global__ void zero_int_kernel(int* __restrict__ p, int n) {
    int i = blockIdx.x * blockDim.x + threadIdx.x;
    if (i < n) p[i] = 0;
}

// per-node deg histogram + per-block LDS bucket histogram (one dst read)
__global__ __launch_bounds__(256) void hist_fused_kernel(const int* __restrict__ dst, int E,
                                                         int* __restrict__ deg,
                                                         int* __restrict__ bcnt, int NB) {
    __shared__ int cnt[512];
    for (int i = threadIdx.x; i < NB; i += 256) cnt[i] = 0;
    __syncthreads();
    int base = blockIdx.x * 4096;
    #pragma unroll
    for (int k = 0; k < 16; ++k) {
        int i = base + k * 256 + threadIdx.x;
        if (i < E) {
            int d = dst[i];
            atomicAdd(&deg[d], 1);
            atomicAdd(&cnt[d >> NB_SHIFT], 1);
        }
    }
    __syncthreads();
    for (int i = threadIdx.x; i < NB; i += 256)
        if (cnt[i]) atomicAdd(&bcnt[i], cnt[i]);
}

// ---- multi-block scan for rowptr: 1024 elements per 256-thread block ----
#define SCAN_PER 1024

__global__ __launch_bounds__(256) void scan_reduce_kernel(const int* __restrict__ deg,
                                                          int* __restrict__ bsum, int N) {
    int t = threadIdx.x;
    int base = blockIdx.x * SCAN_PER + t * 4;
    int4 v = make_int4(0, 0, 0, 0);
    if (base + 3 < N) v = *reinterpret_cast<const int4*>(&deg[base]);
    else {
        if (base + 0 < N) v.x = deg[base + 0];
        if (base + 1 < N) v.y = deg[base + 1];
        if (base + 2 < N) v.z = deg[base + 2];
    }
    int s = v.x + v.y + v.z + v.w;
    #pragma unroll
    for (int m = 1; m < 64; m <<= 1) s += __shfl_xor(s, m);
    __shared__ int ws[4];
    if ((t & 63) == 0) ws[t >> 6] = s;
    __syncthreads();
    if (t == 0) bsum[blockIdx.x] = ws[0] + ws[1] + ws[2] + ws[3];
}

__global__ __launch_bounds__(256) void scan_bsum_kernel(int* __restrict__ bsum, int nb,
                                                        int* __restrict__ rowptr, int N) {
    int t = threadIdx.x;
    int v = (t < nb) ? bsum[t] : 0;
    int s = v;
    #pragma unroll
    for (int d = 1; d < 64; d <<= 1) {
        int o = __shfl_up(s, d);
        if ((t & 63) >= d) s += o;
    }
    __shared__ int ws[4];
    if ((t & 63) == 63) ws[t >> 6] = s;
    __syncthreads();
    int woff = 0;
    int wid = t >> 6;
    for (int w = 0; w < 4; ++w) woff += (w < wid) ? ws[w] : 0;
    int excl = s - v + woff;
    if (t < nb) bsum[t] = excl;
    if (t == 255) rowptr[N] = excl + v;  // grand total
}

__global__ __launch_bounds__(256) void scan_write_kernel(const int* __restrict__ deg,
                                                         const int* __restrict__ bsum,
                                                         int* __restrict__ rowptr, int N) {
    int t = threadIdx.x;
    int base = blockIdx.x * SCAN_PER + t * 4;
    int4 v = make_int4(0, 0, 0, 0);
    if (base + 3 < N) v = *reinterpret_cast<const int4*>(&deg[base]);
    else {
        if (base + 0 < N) v.x = deg[base + 0];
        if (base + 1 < N) v.y = deg[base + 1];
        if (base + 2 < N) v.z = deg[base + 2];
    }
    int s = v.x + v.y + v.z + v.w;
    int incl = s;
    #pragma unroll
    for (int d = 1; d < 64; d <<= 1) {
        int o = __shfl_up(incl, d);
        if ((t & 63) >= d) incl += o;
    }
    __shared__ int ws[4];
    if ((t & 63) == 63) ws[t >> 6] = incl;
    __syncthreads();
    int wid = t >> 6;
    int woff = 0;
    for (int w = 0; w < 4; ++w) woff += (w < wid) ? ws[w] : 0;
    int excl = incl - s + woff + bsum[blockIdx.x];
    if (base + 0 < N) rowptr[base + 0] = excl;
    if (base + 1 < N) rowptr[base + 1] = excl + v.x;
    if (base + 2 < N) rowptr[base + 2] = excl + v.x + v.y;
    if (base + 3 < N) rowptr[base + 3] = excl + v.x + v.y + v.z;
}

// single 512-thread block: exclusive scan of bcnt[NB] -> bbase (+bcur copy), bbase[NB]=E
__global__ __launch_bounds__(512) void scan_bucket_kernel(const int* __restrict__ bcnt, int nb,
                                                          int* __restrict__ bbase,
                                                          int* __restrict__ bcur) {
    int t = threadIdx.x;
    int v = (t < nb) ? bcnt[t] : 0;
    int s = v;
    #pragma unroll
    for (int d = 1; d < 64; d <<= 1) {
        int o = __shfl_up(s, d);
        if ((t & 63) >= d) s += o;
    }
    __shared__ int ws[8];
    if ((t & 63) == 63) ws[t >> 6] = s;
    __syncthreads();
    int wid = t >> 6;
    int woff = 0;
    for (int w = 0; w < 8; ++w) woff += (w < wid) ? ws[w] : 0;
    int excl = s - v + woff;
    if (t < nb) { bbase[t] = excl; bcur[t] = excl; }
    if (t == 511) bbase[nb] = excl + v;  // = E
}

// pass B: scatter (src,dst) pairs into bucket-grouped storage, LDS-rank aggregated
__global__ __launch_bounds__(256) void bucket_scatter_kernel(const int* __restrict__ src,
                                                             const int* __restrict__ dst, int E,
                                                             int* __restrict__ bcur,
                                                             uint2* __restrict__ pairs, int NB) {
    __shared__ int cnt[512];
    __shared__ int base_l[512];
    for (int i = threadIdx.x; i < NB; i += 256) cnt[i] = 0;
    __syncthreads();
    int tbase = blockIdx.x * 4096;
    uint2 e[16];
    int rk[16];
    #pragma unroll
    for (int k = 0; k < 16; ++k) {
        int i = tbase + k * 256 + threadIdx.x;
        if (i < E) {
            e[k].x = (unsigned)src[i];
            e[k].y = (unsigned)dst[i];
            rk[k] = atomicAdd(&cnt[e[k].y >> NB_SHIFT], 1);
        } else {
            rk[k] = -1;
        }
    }
    __syncthreads();
    for (int i = threadIdx.x; i < NB; i += 256)
        base_l[i] = cnt[i] ? atomicAdd(&bcur[i], cnt[i]) : 0;
    __syncthreads();
    #pragma unroll
    for (int k = 0; k < 16; ++k)
        if (rk[k] >= 0) pairs[base_l[e[k].y >> NB_SHIFT] + rk[k]] = e[k];
}

// pass C: one block per bucket; all CSR writes for a bucket from one CU (XCD-local)
__global__ __launch_bounds__(512) void place_kernel(const uint2* __restrict__ pairs,
                                                    const int* __restrict__ bbase,
                                                    const int* __restrict__ rowptr,
                                                    int* __restrict__ cursor,
                                                    int* __restrict__ csr) {
    int b = blockIdx.x;
    int lo = bbase[b], hi = bbase[b + 1];
    for (int j = lo + threadIdx.x; j < hi; j += 512) {
        uint2 p = pairs[j];
        int pos = atomicAdd(&cursor[p.y], 1);
        csr[rowptr[p.y] + pos] = (int)p.x;
    }
}

// ---- GEMM1: hb1 = bf16(x @ W1), plus fused as1/ad1 epilogue ----

#define BM 64
#define BN 64
#define BK 32

__global__ __launch_bounds__(256) void gemm1_kernel(const float* __restrict__ x,
                                                    const float* __restrict__ W,
                                                    const float* __restrict__ a_src,
                                                    const float* __restrict__ a_dst,
                                                    unsigned short* __restrict__ hb1,
                                                    float* __restrict__ as1,
                                                    float* __restrict__ ad1, int N) {
    __shared__ float As[BK][BM + 4];
    __shared__ float Bs[BK][BN + 4];
    int tid = threadIdx.x;
    int row0 = blockIdx.x * BM;
    int ty = tid >> 4;          // 0..15
    int tx = tid & 15;          // 0..15
    float aswr[4], adwr[4];
    #pragma unroll
    for (int j = 0; j < 4; ++j) { aswr[j] = a_src[tx * 4 + j]; adwr[j] = a_dst[tx * 4 + j]; }
    float acc[4][4] = {};
    for (int kt = 0; kt < 512; kt += BK) {
        int r = tid >> 3;               // 0..31
        int kk = (tid & 7) * 4;         // 0..28
        #pragma unroll
        for (int rr = 0; rr < BM; rr += 32) {
            int grow = row0 + r + rr;
            float4 v = make_float4(0.f, 0.f, 0.f, 0.f);
            if (grow < N)
                v = *reinterpret_cast<const float4*>(&x[(size_t)grow * 512 + kt + kk]);
            As[kk + 0][r + rr] = v.x;
            As[kk + 1][r + rr] = v.y;
            As[kk + 2][r + rr] = v.z;
            As[kk + 3][r + rr] = v.w;
        }
        int br = tid >> 4;              // 0..15
        int bc = (tid & 15) * 4;        // 0..60
        #pragma unroll
        for (int rr = 0; rr < BK; rr += 16) {
            float4 v = *reinterpret_cast<const float4*>(&W[(size_t)(kt + br + rr) * 64 + bc]);
            Bs[br + rr][bc + 0] = v.x;
            Bs[br + rr][bc + 1] = v.y;
            Bs[br + rr][bc + 2] = v.z;
            Bs[br + rr][bc + 3] = v.w;
        }
        __syncthreads();
        #pragma unroll
        for (int k = 0; k < BK; ++k) {
            float a[4], b[4];
            #pragma unroll
            for (int i = 0; i < 4; ++i) a[i] = As[k][ty * 4 + i];
            #pragma unroll
            for (int j = 0; j < 4; ++j) b[j] = Bs[k][tx * 4 + j];
            #pragma unroll
            for (int i = 0; i < 4; ++i)
                #pragma unroll
                for (int j = 0; j < 4; ++j) acc[i][j] += a[i] * b[j];
        }
        __syncthreads();
    }
    uint2* hb2p = reinterpret_cast<uint2*>(hb1);
    #pragma unroll
    for (int i = 0; i < 4; ++i) {
        int grow = row0 + ty * 4 + i;
        if (grow < N) {
            uint2 o;
            o.x = f2bf(acc[i][0]) | (f2bf(acc[i][1]) << 16);
            o.y = f2bf(acc[i][2]) | (f2bf(acc[i][3]) << 16);
            hb2p[(size_t)grow * 16 + tx] = o;
            float sa = acc[i][0] * aswr[0] + acc[i][1] * aswr[1] +
                       acc[i][2] * aswr[2] + acc[i][3] * aswr[3];
            float sd = acc[i][0] * adwr[0] + acc[i][1] * adwr[1] +
                       acc[i][2] * adwr[2] + acc[i][3] * adwr[3];
            sa += __shfl_xor(sa, 1);
            sd += __shfl_xor(sd, 1);
            if ((tx & 1) == 0) {
                as1[grow * 8 + (tx >> 1)] = sa;
                ad1[grow * 8 + (tx >> 1)] = sd;
            }
        }
    }
}

// ---- layer-1 attention: fused online softmax + aggregation (1 wave/dst, 4 edges/iter) ----

__global__ __launch_bounds__(256) void attn1_kernel(
    const unsigned short* __restrict__ hb1, const float* __restrict__ as1,
    const float* __restrict__ ad1, const int* __restrict__ rowptr,
    const int* __restrict__ csr_src, const float* __restrict__ b1,
    float* __restrict__ helu, int N) {
    int wv = threadIdx.x >> 6;
    int lane = threadIdx.x & 63;
    int d = blockIdx.x * 4 + wv;
    if (d >= N) return;
    int beg = rowptr[d];
    int edeg = rowptr[d + 1] - beg;
    int tot = edeg + 1;  // + virtual self loop (src = d)
    int q = lane & 15, g = lane >> 4, hh = q >> 1;
    float adh = ad1[d * 8 + hh];
    const uint2* hb = reinterpret_cast<const uint2*>(hb1);
    float m = -1e30f, s = 0.f, a0 = 0.f, a1 = 0.f, a2 = 0.f, a3 = 0.f;
    for (int p0 = 0; p0 < tot; p0 += 4) {
        int p = p0 + g;
        bool valid = p < tot;
        int sn = (p < edeg) ? csr_src[beg + p] : d;
        float e = as1[sn * 8 + hh] + adh;
        e = fmaxf(e, NEG_SLOPE * e);
        float nm = valid ? fmaxf(m, e) : m;
        float sc = __expf(m - nm);
        float w = valid ? __expf(e - nm) : 0.f;
        uint2 u = hb[(size_t)sn * 16 + q];
        float f0, f1, f2, f3;
        bf2x4(u, f0, f1, f2, f3);
        s = fmaf(s, sc, w);
        a0 = fmaf(a0, sc, w * f0);
        a1 = fmaf(a1, sc, w * f1);
        a2 = fmaf(a2, sc, w * f2);
        a3 = fmaf(a3, sc, w * f3);
        m = nm;
    }
    #pragma unroll
    for (int mask = 16; mask < 64; mask <<= 1) {
        float om = __shfl_xor(m, mask), os = __shfl_xor(s, mask);
        float o0 = __shfl_xor(a0, mask), o1 = __shfl_xor(a1, mask);
        float o2 = __shfl_xor(a2, mask), o3 = __shfl_xor(a3, mask);
        float nm = fmaxf(m, om);
        float x1 = __expf(m - nm), x2 = __expf(om - nm);
        s = s * x1 + os * x2;
        a0 = a0 * x1 + o0 * x2;
        a1 = a1 * x1 + o1 * x2;
        a2 = a2 * x1 + o2 * x2;
        a3 = a3 * x1 + o3 * x2;
        m = nm;
    }
    if (lane < 16) {
        float inv = 1.f / (s + 1e-16f);
        const float4 bv = *reinterpret_cast<const float4*>(&b1[q * 4]);
        float4 o;
        o.x = fmaf(a0, inv, bv.x);
        o.y = fmaf(a1, inv, bv.y);
        o.z = fmaf(a2, inv, bv.z);
        o.w = fmaf(a3, inv, bv.w);
        o.x = (o.x > 0.f) ? o.x : (__expf(o.x) - 1.f);
        o.y = (o.y > 0.f) ? o.y : (__expf(o.y) - 1.f);
        o.z = (o.z > 0.f) ? o.z : (__expf(o.z) - 1.f);
        o.w = (o.w > 0.f) ? o.w : (__expf(o.w) - 1.f);
        *reinterpret_cast<float4*>(&helu[(size_t)d * 64 + q * 4]) = o;
    }
}

// ---- GEMM2 (64x64) + alpha2, one wave per row; bf16 h2 out ----

__global__ __launch_bounds__(256) void gemm2_kernel(
    const float* __restrict__ helu, const float* __restrict__ W2,
    const float* __restrict__ a_src2, const float* __restrict__ a_dst2,
    unsigned short* __restrict__ hb2, float* __restrict__ as2, float* __restrict__ ad2, int N) {
    __shared__ float Ws[64 * 64];
    __shared__ float asw[64], adw[64];
    int tid = threadIdx.x;
    for (int i = tid; i < 64 * 64; i += 256) Ws[i] = W2[i];
    if (tid < 64) { asw[tid] = a_src2[tid]; adw[tid] = a_dst2[tid]; }
    __syncthreads();
    int lane = tid & 63, wv = tid >> 6;
    int stride = gridDim.x * 4;
    for (int row = blockIdx.x * 4 + wv; row < N; row += stride) {
        float hv = helu[(size_t)row * 64 + lane];
        float acc = 0.f;
        #pragma unroll
        for (int k = 0; k < 64; ++k) {
            float v = __shfl(hv, k);
            acc += v * Ws[k * 64 + lane];
        }
        hb2[(size_t)row * 64 + lane] = (unsigned short)f2bf(acc);
        float pa = acc * asw[lane];
        float pb = acc * adw[lane];
        #pragma unroll
        for (int mask = 1; mask < 64; mask <<= 1) {
            pa += __shfl_xor(pa, mask);
            pb += __shfl_xor(pb, mask);
        }
        if (lane == 0) { as2[row] = pa; ad2[row] = pb; }
    }
}

// ---- layer-2 attention + log_softmax (fused online softmax, 4 edges/iter) ----

__global__ __launch_bounds__(256) void attn2_kernel(
    const unsigned short* __restrict__ hb2, const float* __restrict__ as2,
    const float* __restrict__ ad2, const int* __restrict__ rowptr,
    const int* __restrict__ csr_src, const float* __restrict__ b2,
    float* __restrict__ out, int N) {
    int wv = threadIdx.x >> 6;
    int lane = threadIdx.x & 63;
    int d = blockIdx.x * 4 + wv;
    if (d >= N) return;
    int beg = rowptr[d];
    int edeg = rowptr[d + 1] - beg;
    int tot = edeg + 1;
    int q = lane & 15, g = lane >> 4;
    float add = ad2[d];
    const uint2* hb = reinterpret_cast<const uint2*>(hb2);
    float m = -1e30f, s = 0.f, a0 = 0.f, a1 = 0.f, a2 = 0.f, a3 = 0.f;
    for (int p0 = 0; p0 < tot; p0 += 4) {
        int p = p0 + g;
        bool valid = p < tot;
        int sn = (p < edeg) ? csr_src[beg + p] : d;
        float e = as2[sn] + add;
        e = fmaxf(e, NEG_SLOPE * e);
        float nm = valid ? fmaxf(m, e) : m;
        float sc = __expf(m - nm);
        float w = valid ? __expf(e - nm) : 0.f;
        uint2 u = hb[(size_t)sn * 16 + q];
        float f0, f1, f2, f3;
        bf2x4(u, f0, f1, f2, f3);
        s = fmaf(s, sc, w);
        a0 = fmaf(a0, sc, w * f0);
        a1 = fmaf(a1, sc, w * f1);
        a2 = fmaf(a2, sc, w * f2);
        a3 = fmaf(a3, sc, w * f3);
        m = nm;
    }
    #pragma unroll
    for (int mask = 16; mask < 64; mask <<= 1) {
        float om = __shfl_xor(m, mask), os = __shfl_xor(s, mask);
        float o0 = __shfl_xor(a0, mask), o1 = __shfl_xor(a1, mask);
        float o2 = __shfl_xor(a2, mask), o3 = __shfl_xor(a3, mask);
        float nm = fmaxf(m, om);
        float x1 = __expf(m - nm), x2 = __expf(om - nm);
        s = s * x1 + os * x2;
        a0 = a0 * x1 + o0 * x2;
        a1 = a1 * x1 + o1 * x2;
        a2 = a2 * x1 + o2 * x2;
        a3 = a3 * x1 + o3 * x2;
        m = nm;
    }
    float inv = 1.f / (s + 1e-16f);
    const float4 bv = *reinterpret_cast<const float4*>(&b2[q * 4]);
    float o0 = fmaf(a0, inv, bv.x);
    float o1 = fmaf(a1, inv, bv.y);
    float o2 = fmaf(a2, inv, bv.z);
    float o3 = fmaf(a3, inv, bv.w);
    float mx = fmaxf(fmaxf(o0, o1), fmaxf(o2, o3));
    #pragma unroll
    for (int mask = 1; mask < 16; mask <<= 1) mx = fmaxf(mx, __shfl_xor(mx, mask));
    float sm = __expf(o0 - mx) + __expf(o1 - mx) + __expf(o2 - mx) + __expf(o3 - mx);
    #pragma unroll
    for (int mask = 1; mask < 16; mask <<= 1) sm += __shfl_xor(sm, mask);
    float lse = mx + __logf(sm);
    if (lane < 16) {
        float4 o;
        o.x = o0 - lse; o.y = o1 - lse; o.z = o2 - lse; o.w = o3 - lse;
        *reinterpret_cast<float4*>(&out[(size_t)d * 64 + q * 4]) = o;
    }
}

// ---------------- launch ----------------

extern "C" void kernel_launch(void* const* d_in, const int* in_sizes, int n_in,
                              void* d_out, int out_size, void* d_ws, size_t ws_size,
                              hipStream_t stream) {
    const float* x      = (const float*)d_in[0];
    const int*   ei     = (const int*)d_in[1];
    const float* W1     = (const float*)d_in[2];
    const float* a_src1 = (const float*)d_in[3];
    const float* a_dst1 = (const float*)d_in[4];
    const float* b1     = (const float*)d_in[5];
    const float* W2     = (const float*)d_in[6];
    const float* a_src2 = (const float*)d_in[7];
    const float* a_dst2 = (const float*)d_in[8];
    const float* b2     = (const float*)d_in[9];

    int N = in_sizes[0] / 512;
    int E = in_sizes[1] / 2;
    const int* src = ei;
    const int* dst = ei + E;
    int NB = (N + 255) >> NB_SHIFT;          // 391 buckets of 256 nodes

    char* w = (char*)d_ws;
    size_t off = 0;
    auto alloc = [&](size_t bytes) -> void* {
        off = (off + 255) & ~(size_t)255;
        void* p = w + off;
        off += bytes;
        return p;
    };
    int* deg    = (int*)alloc((size_t)(2 * N + NB + 8) * sizeof(int));
    int* cursor = deg + N;
    int* bcnt   = deg + 2 * N;
    int* rowptr = (int*)alloc((size_t)(N + 1) * sizeof(int));
    int nb = (N + SCAN_PER - 1) / SCAN_PER;
    int* bsum   = (int*)alloc((size_t)nb * sizeof(int));
    int* bbase  = (int*)alloc((size_t)(NB + 1) * sizeof(int));
    int* bcur   = (int*)alloc((size_t)NB * sizeof(int));
    int* csr    = (int*)alloc((size_t)E * sizeof(int));
    unsigned short* hb1 = (unsigned short*)alloc((size_t)N * 64 * sizeof(unsigned short));
    float* as1  = (float*)alloc((size_t)N * 8 * sizeof(float));
    float* ad1  = (float*)alloc((size_t)N * 8 * sizeof(float));
    float* helu = (float*)alloc((size_t)N * 64 * sizeof(float));
    uint2* pairs = (uint2*)helu;             // alias: pairs dead before attn1 writes helu
    unsigned short* hb2 = hb1;               // aliases: hb1/as1/ad1 dead after attn1
    float* as2 = as1;
    float* ad2 = ad1;

    int eb = (E + 4095) / 4096;

    zero_int_kernel<<<(2 * N + NB + 255) / 256, 256, 0, stream>>>(deg, 2 * N + NB);
    hist_fused_kernel<<<eb, 256, 0, stream>>>(dst, E, deg, bcnt, NB);
    scan_reduce_kernel<<<nb, 256, 0, stream>>>(deg, bsum, N);
    scan_bsum_kernel<<<1, 256, 0, stream>>>(bsum, nb, rowptr, N);
    scan_write_kernel<<<nb, 256, 0, stream>>>(deg, bsum, rowptr, N);
    scan_bucket_kernel<<<1, 512, 0, stream>>>(bcnt, NB, bbase, bcur);
    bucket_scatter_kernel<<<eb, 256, 0, stream>>>(src, dst, E, bcur, pairs, NB);
    place_kernel<<<NB, 512, 0, stream>>>(pairs, bbase, rowptr, cursor, csr);

    gemm1_kernel<<<(N + BM - 1) / BM, 256, 0, stream>>>(x, W1, a_src1, a_dst1, hb1, as1, ad1, N);
    attn1_kernel<<<(N + 3) / 4, 256, 0, stream>>>(hb1, as1, ad1, rowptr, csr, b1, helu, N);

    gemm2_kernel<<<2048, 256, 0, stream>>>(helu, W2, a_src2, a_dst2, hb2, as2, ad2, N);
    attn2_kernel<<<(N + 3) / 4, 256, 0, stream>>>(hb2, as2, ad2, rowptr, csr, b2, (float*)d_out, N);
}

// Round 6
// 520.682 us; speedup vs baseline: 2.6153x; 1.3470x over previous
//
#include <hip/hip_runtime.h>

#define NEG_SLOPE 0.2f
#define NB_SHIFT 8          // bucket = dst >> 8 (256-node windows)

// bf16 helpers (RNE pack, cheap unpack)
__device__ inline unsigned f2bf(float f) {
    unsigned u = __float_as_uint(f);
    return (u + 0x7fffu + ((u >> 16) & 1u)) >> 16;
}
__device__ inline void bf2x4(uint2 u, float& f0, float& f1, float& f2, float& f3) {
    f0 = __uint_as_float(u.x << 16);
    f1 = __uint_as_float(u.x & 0xffff0000u);
    f2 = __uint_as_float(u.y << 16);
    f3 = __uint_as_float(u.y & 0xffff0000u);
}

// ---------------- CSR build (no per-edge global atomics) ----------------

__global__ void zero_int_kernel(int* __restrict__ p, int n) {
    int i = blockIdx.x * blockDim.x + threadIdx.x;
    if (i < n) p[i] = 0;
}

// bucket histogram only: LDS counters, one global atomic per bucket per block
__global__ __launch_bounds__(256) void bucket_count_kernel(const int* __restrict__ dst, int E,
                                                           int* __restrict__ bcnt, int NB) {
    __shared__ int cnt[512];
    for (int i = threadIdx.x; i < NB; i += 256) cnt[i] = 0;
    __syncthreads();
    int base = blockIdx.x * 16384;
    for (int k = 0; k < 64; ++k) {
        int i = base + k * 256 + threadIdx.x;
        if (i < E) atomicAdd(&cnt[dst[i] >> NB_SHIFT], 1);
    }
    __syncthreads();
    for (int i = threadIdx.x; i < NB; i += 256)
        if (cnt[i]) atomicAdd(&bcnt[i], cnt[i]);
}

// single 512-thread block: exclusive scan of bcnt[NB] -> bbase (+bcur copy); bbase[NB]=rowptr[N]=E
__global__ __launch_bounds__(512) void scan_bucket_kernel(const int* __restrict__ bcnt, int nb,
                                                          int* __restrict__ bbase,
                                                          int* __restrict__ bcur,
                                                          int* __restrict__ rowptr, int N) {
    int t = threadIdx.x;
    int v = (t < nb) ? bcnt[t] : 0;
    int s = v;
    #pragma unroll
    for (int d = 1; d < 64; d <<= 1) {
        int o = __shfl_up(s, d);
        if ((t & 63) >= d) s += o;
    }
    __shared__ int ws[8];
    if ((t & 63) == 63) ws[t >> 6] = s;
    __syncthreads();
    int wid = t >> 6;
    int woff = 0;
    for (int w = 0; w < 8; ++w) woff += (w < wid) ? ws[w] : 0;
    int excl = s - v + woff;
    if (t < nb) { bbase[t] = excl; bcur[t] = excl; }
    if (t == 511) { bbase[nb] = excl + v; rowptr[N] = excl + v; }  // grand total = E
}

// scatter (src,dst) pairs into bucket-grouped storage, LDS-rank aggregated; 8192 edges/block
__global__ __launch_bounds__(256) void bucket_scatter_kernel(const int* __restrict__ src,
                                                             const int* __restrict__ dst, int E,
                                                             int* __restrict__ bcur,
                                                             uint2* __restrict__ pairs, int NB) {
    __shared__ int cnt[512];
    __shared__ int base_l[512];
    for (int i = threadIdx.x; i < NB; i += 256) cnt[i] = 0;
    __syncthreads();
    int tbase = blockIdx.x * 8192;
    uint2 e[32];
    int rk[32];
    #pragma unroll
    for (int k = 0; k < 32; ++k) {
        int i = tbase + k * 256 + threadIdx.x;
        if (i < E) {
            e[k].x = (unsigned)src[i];
            e[k].y = (unsigned)dst[i];
            rk[k] = atomicAdd(&cnt[e[k].y >> NB_SHIFT], 1);
        } else {
            rk[k] = -1;
        }
    }
    __syncthreads();
    for (int i = threadIdx.x; i < NB; i += 256)
        base_l[i] = cnt[i] ? atomicAdd(&bcur[i], cnt[i]) : 0;
    __syncthreads();
    #pragma unroll
    for (int k = 0; k < 32; ++k)
        if (rk[k] >= 0) pairs[base_l[e[k].y >> NB_SHIFT] + rk[k]] = e[k];
}

// one block per bucket: LDS degree count -> local scan -> rowptr write -> LDS-cursor place
__global__ __launch_bounds__(512) void build_csr_kernel(const uint2* __restrict__ pairs,
                                                        const int* __restrict__ bbase,
                                                        int* __restrict__ rowptr,
                                                        int* __restrict__ csr, int N) {
    __shared__ int cnt[256];
    __shared__ int cur[256];
    __shared__ int ws[4];
    int b = blockIdx.x;
    int lo = bbase[b], hi = bbase[b + 1];
    int t = threadIdx.x;
    if (t < 256) cnt[t] = 0;
    __syncthreads();
    for (int j = lo + t; j < hi; j += 512)
        atomicAdd(&cnt[pairs[j].y & 255], 1);
    __syncthreads();
    int v = 0, s = 0;
    if (t < 256) {
        v = cnt[t];
        s = v;
        #pragma unroll
        for (int d = 1; d < 64; d <<= 1) {
            int o = __shfl_up(s, d);
            if ((t & 63) >= d) s += o;
        }
        if ((t & 63) == 63) ws[t >> 6] = s;
    }
    __syncthreads();
    if (t < 256) {
        int wid = t >> 6;
        int woff = 0;
        for (int w2 = 0; w2 < 4; ++w2) woff += (w2 < wid) ? ws[w2] : 0;
        int excl = lo + s - v + woff;
        int node = (b << NB_SHIFT) + t;
        if (node < N) rowptr[node] = excl;
        cur[t] = excl;
    }
    __syncthreads();
    for (int j = lo + t; j < hi; j += 512) {
        uint2 p = pairs[j];
        int pos = atomicAdd(&cur[p.y & 255], 1);   // LDS atomic
        csr[pos] = (int)p.x;
    }
}

// ---- GEMM1: hb1 = bf16(x @ W1), plus fused as1/ad1 epilogue ----

#define BM 64
#define BN 64
#define BK 32

__global__ __launch_bounds__(256) void gemm1_kernel(const float* __restrict__ x,
                                                    const float* __restrict__ W,
                                                    const float* __restrict__ a_src,
                                                    const float* __restrict__ a_dst,
                                                    unsigned short* __restrict__ hb1,
                                                    float* __restrict__ as1,
                                                    float* __restrict__ ad1, int N) {
    __shared__ float As[BK][BM + 4];
    __shared__ float Bs[BK][BN + 4];
    int tid = threadIdx.x;
    int row0 = blockIdx.x * BM;
    int ty = tid >> 4;          // 0..15
    int tx = tid & 15;          // 0..15
    float aswr[4], adwr[4];
    #pragma unroll
    for (int j = 0; j < 4; ++j) { aswr[j] = a_src[tx * 4 + j]; adwr[j] = a_dst[tx * 4 + j]; }
    float acc[4][4] = {};
    for (int kt = 0; kt < 512; kt += BK) {
        int r = tid >> 3;               // 0..31
        int kk = (tid & 7) * 4;         // 0..28
        #pragma unroll
        for (int rr = 0; rr < BM; rr += 32) {
            int grow = row0 + r + rr;
            float4 v = make_float4(0.f, 0.f, 0.f, 0.f);
            if (grow < N)
                v = *reinterpret_cast<const float4*>(&x[(size_t)grow * 512 + kt + kk]);
            As[kk + 0][r + rr] = v.x;
            As[kk + 1][r + rr] = v.y;
            As[kk + 2][r + rr] = v.z;
            As[kk + 3][r + rr] = v.w;
        }
        int br = tid >> 4;              // 0..15
        int bc = (tid & 15) * 4;        // 0..60
        #pragma unroll
        for (int rr = 0; rr < BK; rr += 16) {
            float4 v = *reinterpret_cast<const float4*>(&W[(size_t)(kt + br + rr) * 64 + bc]);
            Bs[br + rr][bc + 0] = v.x;
            Bs[br + rr][bc + 1] = v.y;
            Bs[br + rr][bc + 2] = v.z;
            Bs[br + rr][bc + 3] = v.w;
        }
        __syncthreads();
        #pragma unroll
        for (int k = 0; k < BK; ++k) {
            float a[4], b[4];
            #pragma unroll
            for (int i = 0; i < 4; ++i) a[i] = As[k][ty * 4 + i];
            #pragma unroll
            for (int j = 0; j < 4; ++j) b[j] = Bs[k][tx * 4 + j];
            #pragma unroll
            for (int i = 0; i < 4; ++i)
                #pragma unroll
                for (int j = 0; j < 4; ++j) acc[i][j] += a[i] * b[j];
        }
        __syncthreads();
    }
    uint2* hb2p = reinterpret_cast<uint2*>(hb1);
    #pragma unroll
    for (int i = 0; i < 4; ++i) {
        int grow = row0 + ty * 4 + i;
        if (grow < N) {
            uint2 o;
            o.x = f2bf(acc[i][0]) | (f2bf(acc[i][1]) << 16);
            o.y = f2bf(acc[i][2]) | (f2bf(acc[i][3]) << 16);
            hb2p[(size_t)grow * 16 + tx] = o;
            float sa = acc[i][0] * aswr[0] + acc[i][1] * aswr[1] +
                       acc[i][2] * aswr[2] + acc[i][3] * aswr[3];
            float sd = acc[i][0] * adwr[0] + acc[i][1] * adwr[1] +
                       acc[i][2] * adwr[2] + acc[i][3] * adwr[3];
            sa += __shfl_xor(sa, 1);
            sd += __shfl_xor(sd, 1);
            if ((tx & 1) == 0) {
                as1[grow * 8 + (tx >> 1)] = sa;
                ad1[grow * 8 + (tx >> 1)] = sd;
            }
        }
    }
}

// ---- layer-1 attention: fused online softmax + aggregation (1 wave/dst, 4 edges/iter) ----

__global__ __launch_bounds__(256) void attn1_kernel(
    const unsigned short* __restrict__ hb1, const float* __restrict__ as1,
    const float* __restrict__ ad1, const int* __restrict__ rowptr,
    const int* __restrict__ csr_src, const float* __restrict__ b1,
    float* __restrict__ helu, int N) {
    int wv = threadIdx.x >> 6;
    int lane = threadIdx.x & 63;
    int d = blockIdx.x * 4 + wv;
    if (d >= N) return;
    int beg = rowptr[d];
    int edeg = rowptr[d + 1] - beg;
    int tot = edeg + 1;  // + virtual self loop (src = d)
    int q = lane & 15, g = lane >> 4, hh = q >> 1;
    float adh = ad1[d * 8 + hh];
    const uint2* hb = reinterpret_cast<const uint2*>(hb1);
    float m = -1e30f, s = 0.f, a0 = 0.f, a1 = 0.f, a2 = 0.f, a3 = 0.f;
    for (int p0 = 0; p0 < tot; p0 += 4) {
        int p = p0 + g;
        bool valid = p < tot;
        int sn = (p < edeg) ? csr_src[beg + p] : d;
        float e = as1[sn * 8 + hh] + adh;
        e = fmaxf(e, NEG_SLOPE * e);
        float nm = valid ? fmaxf(m, e) : m;
        float sc = __expf(m - nm);
        float w = valid ? __expf(e - nm) : 0.f;
        uint2 u = hb[(size_t)sn * 16 + q];
        float f0, f1, f2, f3;
        bf2x4(u, f0, f1, f2, f3);
        s = fmaf(s, sc, w);
        a0 = fmaf(a0, sc, w * f0);
        a1 = fmaf(a1, sc, w * f1);
        a2 = fmaf(a2, sc, w * f2);
        a3 = fmaf(a3, sc, w * f3);
        m = nm;
    }
    #pragma unroll
    for (int mask = 16; mask < 64; mask <<= 1) {
        float om = __shfl_xor(m, mask), os = __shfl_xor(s, mask);
        float o0 = __shfl_xor(a0, mask), o1 = __shfl_xor(a1, mask);
        float o2 = __shfl_xor(a2, mask), o3 = __shfl_xor(a3, mask);
        float nm = fmaxf(m, om);
        float x1 = __expf(m - nm), x2 = __expf(om - nm);
        s = s * x1 + os * x2;
        a0 = a0 * x1 + o0 * x2;
        a1 = a1 * x1 + o1 * x2;
        a2 = a2 * x1 + o2 * x2;
        a3 = a3 * x1 + o3 * x2;
        m = nm;
    }
    if (lane < 16) {
        float inv = 1.f / (s + 1e-16f);
        const float4 bv = *reinterpret_cast<const float4*>(&b1[q * 4]);
        float4 o;
        o.x = fmaf(a0, inv, bv.x);
        o.y = fmaf(a1, inv, bv.y);
        o.z = fmaf(a2, inv, bv.z);
        o.w = fmaf(a3, inv, bv.w);
        o.x = (o.x > 0.f) ? o.x : (__expf(o.x) - 1.f);
        o.y = (o.y > 0.f) ? o.y : (__expf(o.y) - 1.f);
        o.z = (o.z > 0.f) ? o.z : (__expf(o.z) - 1.f);
        o.w = (o.w > 0.f) ? o.w : (__expf(o.w) - 1.f);
        *reinterpret_cast<float4*>(&helu[(size_t)d * 64 + q * 4]) = o;
    }
}

// ---- GEMM2 (64x64) + alpha2, one wave per row; bf16 h2 out ----

__global__ __launch_bounds__(256) void gemm2_kernel(
    const float* __restrict__ helu, const float* __restrict__ W2,
    const float* __restrict__ a_src2, const float* __restrict__ a_dst2,
    unsigned short* __restrict__ hb2, float* __restrict__ as2, float* __restrict__ ad2, int N) {
    __shared__ float Ws[64 * 64];
    __shared__ float asw[64], adw[64];
    int tid = threadIdx.x;
    for (int i = tid; i < 64 * 64; i += 256) Ws[i] = W2[i];
    if (tid < 64) { asw[tid] = a_src2[tid]; adw[tid] = a_dst2[tid]; }
    __syncthreads();
    int lane = tid & 63, wv = tid >> 6;
    int stride = gridDim.x * 4;
    for (int row = blockIdx.x * 4 + wv; row < N; row += stride) {
        float hv = helu[(size_t)row * 64 + lane];
        float acc = 0.f;
        #pragma unroll
        for (int k = 0; k < 64; ++k) {
            float v = __shfl(hv, k);
            acc += v * Ws[k * 64 + lane];
        }
        hb2[(size_t)row * 64 + lane] = (unsigned short)f2bf(acc);
        float pa = acc * asw[lane];
        float pb = acc * adw[lane];
        #pragma unroll
        for (int mask = 1; mask < 64; mask <<= 1) {
            pa += __shfl_xor(pa, mask);
            pb += __shfl_xor(pb, mask);
        }
        if (lane == 0) { as2[row] = pa; ad2[row] = pb; }
    }
}

// ---- layer-2 attention + log_softmax (fused online softmax, 4 edges/iter) ----

__global__ __launch_bounds__(256) void attn2_kernel(
    const unsigned short* __restrict__ hb2, const float* __restrict__ as2,
    const float* __restrict__ ad2, const int* __restrict__ rowptr,
    const int* __restrict__ csr_src, const float* __restrict__ b2,
    float* __restrict__ out, int N) {
    int wv = threadIdx.x >> 6;
    int lane = threadIdx.x & 63;
    int d = blockIdx.x * 4 + wv;
    if (d >= N) return;
    int beg = rowptr[d];
    int edeg = rowptr[d + 1] - beg;
    int tot = edeg + 1;
    int q = lane & 15, g = lane >> 4;
    float add = ad2[d];
    const uint2* hb = reinterpret_cast<const uint2*>(hb2);
    float m = -1e30f, s = 0.f, a0 = 0.f, a1 = 0.f, a2 = 0.f, a3 = 0.f;
    for (int p0 = 0; p0 < tot; p0 += 4) {
        int p = p0 + g;
        bool valid = p < tot;
        int sn = (p < edeg) ? csr_src[beg + p] : d;
        float e = as2[sn] + add;
        e = fmaxf(e, NEG_SLOPE * e);
        float nm = valid ? fmaxf(m, e) : m;
        float sc = __expf(m - nm);
        float w = valid ? __expf(e - nm) : 0.f;
        uint2 u = hb[(size_t)sn * 16 + q];
        float f0, f1, f2, f3;
        bf2x4(u, f0, f1, f2, f3);
        s = fmaf(s, sc, w);
        a0 = fmaf(a0, sc, w * f0);
        a1 = fmaf(a1, sc, w * f1);
        a2 = fmaf(a2, sc, w * f2);
        a3 = fmaf(a3, sc, w * f3);
        m = nm;
    }
    #pragma unroll
    for (int mask = 16; mask < 64; mask <<= 1) {
        float om = __shfl_xor(m, mask), os = __shfl_xor(s, mask);
        float o0 = __shfl_xor(a0, mask), o1 = __shfl_xor(a1, mask);
        float o2 = __shfl_xor(a2, mask), o3 = __shfl_xor(a3, mask);
        float nm = fmaxf(m, om);
        float x1 = __expf(m - nm), x2 = __expf(om - nm);
        s = s * x1 + os * x2;
        a0 = a0 * x1 + o0 * x2;
        a1 = a1 * x1 + o1 * x2;
        a2 = a2 * x1 + o2 * x2;
        a3 = a3 * x1 + o3 * x2;
        m = nm;
    }
    float inv = 1.f / (s + 1e-16f);
    const float4 bv = *reinterpret_cast<const float4*>(&b2[q * 4]);
    float o0 = fmaf(a0, inv, bv.x);
    float o1 = fmaf(a1, inv, bv.y);
    float o2 = fmaf(a2, inv, bv.z);
    float o3 = fmaf(a3, inv, bv.w);
    float mx = fmaxf(fmaxf(o0, o1), fmaxf(o2, o3));
    #pragma unroll
    for (int mask = 1; mask < 16; mask <<= 1) mx = fmaxf(mx, __shfl_xor(mx, mask));
    float sm = __expf(o0 - mx) + __expf(o1 - mx) + __expf(o2 - mx) + __expf(o3 - mx);
    #pragma unroll
    for (int mask = 1; mask < 16; mask <<= 1) sm += __shfl_xor(sm, mask);
    float lse = mx + __logf(sm);
    if (lane < 16) {
        float4 o;
        o.x = o0 - lse; o.y = o1 - lse; o.z = o2 - lse; o.w = o3 - lse;
        *reinterpret_cast<float4*>(&out[(size_t)d * 64 + q * 4]) = o;
    }
}

// ---------------- launch ----------------

extern "C" void kernel_launch(void* const* d_in, const int* in_sizes, int n_in,
                              void* d_out, int out_size, void* d_ws, size_t ws_size,
                              hipStream_t stream) {
    const float* x      = (const float*)d_in[0];
    const int*   ei     = (const int*)d_in[1];
    const float* W1     = (const float*)d_in[2];
    const float* a_src1 = (const float*)d_in[3];
    const float* a_dst1 = (const float*)d_in[4];
    const float* b1     = (const float*)d_in[5];
    const float* W2     = (const float*)d_in[6];
    const float* a_src2 = (const float*)d_in[7];
    const float* a_dst2 = (const float*)d_in[8];
    const float* b2     = (const float*)d_in[9];

    int N = in_sizes[0] / 512;
    int E = in_sizes[1] / 2;
    const int* src = ei;
    const int* dst = ei + E;
    int NB = (N + 255) >> NB_SHIFT;          // 391 buckets of 256 nodes

    char* w = (char*)d_ws;
    size_t off = 0;
    auto alloc = [&](size_t bytes) -> void* {
        off = (off + 255) & ~(size_t)255;
        void* p = w + off;
        off += bytes;
        return p;
    };
    int* bcnt   = (int*)alloc((size_t)NB * sizeof(int));
    int* rowptr = (int*)alloc((size_t)(N + 1) * sizeof(int));
    int* bbase  = (int*)alloc((size_t)(NB + 1) * sizeof(int));
    int* bcur   = (int*)alloc((size_t)NB * sizeof(int));
    int* csr    = (int*)alloc((size_t)E * sizeof(int));
    unsigned short* hb1 = (unsigned short*)alloc((size_t)N * 64 * sizeof(unsigned short));
    float* as1  = (float*)alloc((size_t)N * 8 * sizeof(float));
    float* ad1  = (float*)alloc((size_t)N * 8 * sizeof(float));
    float* helu = (float*)alloc((size_t)N * 64 * sizeof(float));
    uint2* pairs = (uint2*)helu;             // alias: pairs dead before attn1 writes helu
    unsigned short* hb2 = hb1;               // aliases: hb1/as1/ad1 dead after attn1
    float* as2 = as1;
    float* ad2 = ad1;

    zero_int_kernel<<<(NB + 255) / 256, 256, 0, stream>>>(bcnt, NB);
    bucket_count_kernel<<<(E + 16383) / 16384, 256, 0, stream>>>(dst, E, bcnt, NB);
    scan_bucket_kernel<<<1, 512, 0, stream>>>(bcnt, NB, bbase, bcur, rowptr, N);
    bucket_scatter_kernel<<<(E + 8191) / 8192, 256, 0, stream>>>(src, dst, E, bcur, pairs, NB);
    build_csr_kernel<<<NB, 512, 0, stream>>>(pairs, bbase, rowptr, csr, N);

    gemm1_kernel<<<(N + BM - 1) / BM, 256, 0, stream>>>(x, W1, a_src1, a_dst1, hb1, as1, ad1, N);
    attn1_kernel<<<(N + 3) / 4, 256, 0, stream>>>(hb1, as1, ad1, rowptr, csr, b1, helu, N);

    gemm2_kernel<<<2048, 256, 0, stream>>>(helu, W2, a_src2, a_dst2, hb2, as2, ad2, N);
    attn2_kernel<<<(N + 3) / 4, 256, 0, stream>>>(hb2, as2, ad2, rowptr, csr, b2, (float*)d_out, N);
}

// Round 7
// 493.334 us; speedup vs baseline: 2.7603x; 1.0554x over previous
//
#include <hip/hip_runtime.h>

#define NEG_SLOPE 0.2f
#define NB_SHIFT 8          // bucket = dst >> 8 (256-node windows)

typedef __attribute__((ext_vector_type(8))) short bf16x8;
typedef __attribute__((ext_vector_type(4))) float f32x4;

// bf16 helpers (RNE pack, cheap unpack)
__device__ inline unsigned f2bf(float f) {
    unsigned u = __float_as_uint(f);
    return (u + 0x7fffu + ((u >> 16) & 1u)) >> 16;
}
__device__ inline void bf2x4(uint2 u, float& f0, float& f1, float& f2, float& f3) {
    f0 = __uint_as_float(u.x << 16);
    f1 = __uint_as_float(u.x & 0xffff0000u);
    f2 = __uint_as_float(u.y << 16);
    f3 = __uint_as_float(u.y & 0xffff0000u);
}

// ---------------- CSR build (no per-edge global atomics) ----------------

__global__ void zero_int_kernel(int* __restrict__ p, int n) {
    int i = blockIdx.x * blockDim.x + threadIdx.x;
    if (i < n) p[i] = 0;
}

// bucket histogram only: LDS counters, one global atomic per bucket per block
__global__ __launch_bounds__(256) void bucket_count_kernel(const int* __restrict__ dst, int E,
                                                           int* __restrict__ bcnt, int NB) {
    __shared__ int cnt[512];
    for (int i = threadIdx.x; i < NB; i += 256) cnt[i] = 0;
    __syncthreads();
    int base = blockIdx.x * 16384;
    for (int k = 0; k < 64; ++k) {
        int i = base + k * 256 + threadIdx.x;
        if (i < E) atomicAdd(&cnt[dst[i] >> NB_SHIFT], 1);
    }
    __syncthreads();
    for (int i = threadIdx.x; i < NB; i += 256)
        if (cnt[i]) atomicAdd(&bcnt[i], cnt[i]);
}

// single 512-thread block: exclusive scan of bcnt[NB] -> bbase (+bcur copy); bbase[NB]=rowptr[N]=E
__global__ __launch_bounds__(512) void scan_bucket_kernel(const int* __restrict__ bcnt, int nb,
                                                          int* __restrict__ bbase,
                                                          int* __restrict__ bcur,
                                                          int* __restrict__ rowptr, int N) {
    int t = threadIdx.x;
    int v = (t < nb) ? bcnt[t] : 0;
    int s = v;
    #pragma unroll
    for (int d = 1; d < 64; d <<= 1) {
        int o = __shfl_up(s, d);
        if ((t & 63) >= d) s += o;
    }
    __shared__ int ws[8];
    if ((t & 63) == 63) ws[t >> 6] = s;
    __syncthreads();
    int wid = t >> 6;
    int woff = 0;
    for (int w = 0; w < 8; ++w) woff += (w < wid) ? ws[w] : 0;
    int excl = s - v + woff;
    if (t < nb) { bbase[t] = excl; bcur[t] = excl; }
    if (t == 511) { bbase[nb] = excl + v; rowptr[N] = excl + v; }  // grand total = E
}

// scatter (src,dst) pairs into bucket-grouped storage, LDS-rank aggregated; 8192 edges/block
__global__ __launch_bounds__(256) void bucket_scatter_kernel(const int* __restrict__ src,
                                                             const int* __restrict__ dst, int E,
                                                             int* __restrict__ bcur,
                                                             uint2* __restrict__ pairs, int NB) {
    __shared__ int cnt[512];
    __shared__ int base_l[512];
    for (int i = threadIdx.x; i < NB; i += 256) cnt[i] = 0;
    __syncthreads();
    int tbase = blockIdx.x * 8192;
    uint2 e[32];
    int rk[32];
    #pragma unroll
    for (int k = 0; k < 32; ++k) {
        int i = tbase + k * 256 + threadIdx.x;
        if (i < E) {
            e[k].x = (unsigned)src[i];
            e[k].y = (unsigned)dst[i];
            rk[k] = atomicAdd(&cnt[e[k].y >> NB_SHIFT], 1);
        } else {
            rk[k] = -1;
        }
    }
    __syncthreads();
    for (int i = threadIdx.x; i < NB; i += 256)
        base_l[i] = cnt[i] ? atomicAdd(&bcur[i], cnt[i]) : 0;
    __syncthreads();
    #pragma unroll
    for (int k = 0; k < 32; ++k)
        if (rk[k] >= 0) pairs[base_l[e[k].y >> NB_SHIFT] + rk[k]] = e[k];
}

// one block per bucket: LDS degree count -> local scan -> rowptr write -> LDS-cursor place
__global__ __launch_bounds__(512) void build_csr_kernel(const uint2* __restrict__ pairs,
                                                        const int* __restrict__ bbase,
                                                        int* __restrict__ rowptr,
                                                        int* __restrict__ csr, int N) {
    __shared__ int cnt[256];
    __shared__ int cur[256];
    __shared__ int ws[4];
    int b = blockIdx.x;
    int lo = bbase[b], hi = bbase[b + 1];
    int t = threadIdx.x;
    if (t < 256) cnt[t] = 0;
    __syncthreads();
    for (int j = lo + t; j < hi; j += 512)
        atomicAdd(&cnt[pairs[j].y & 255], 1);
    __syncthreads();
    int v = 0, s = 0;
    if (t < 256) {
        v = cnt[t];
        s = v;
        #pragma unroll
        for (int d = 1; d < 64; d <<= 1) {
            int o = __shfl_up(s, d);
            if ((t & 63) >= d) s += o;
        }
        if ((t & 63) == 63) ws[t >> 6] = s;
    }
    __syncthreads();
    if (t < 256) {
        int wid = t >> 6;
        int woff = 0;
        for (int w2 = 0; w2 < 4; ++w2) woff += (w2 < wid) ? ws[w2] : 0;
        int excl = lo + s - v + woff;
        int node = (b << NB_SHIFT) + t;
        if (node < N) rowptr[node] = excl;
        cur[t] = excl;
    }
    __syncthreads();
    for (int j = lo + t; j < hi; j += 512) {
        uint2 p = pairs[j];
        int pos = atomicAdd(&cur[p.y & 255], 1);   // LDS atomic
        csr[pos] = (int)p.x;
    }
}

// ---- GEMM1 (MFMA bf16): hb1 = bf16(x @ W1), fused as1/ad1 epilogue ----
// W1 staged to LDS transposed [col][k] bf16 (+8 pad -> free 2-way conflicts, 16B aligned).
// 4 waves/block, each owns a 16-row strip; K=512 in 16 steps of 32.

__global__ __launch_bounds__(256) void gemm1_kernel(const float* __restrict__ x,
                                                    const float* __restrict__ W,
                                                    const float* __restrict__ a_src,
                                                    const float* __restrict__ a_dst,
                                                    unsigned short* __restrict__ hb1,
                                                    float* __restrict__ as1,
                                                    float* __restrict__ ad1, int N) {
    __shared__ unsigned short Wl[64][520];
    int tid = threadIdx.x;
    for (int i = tid; i < 512 * 16; i += 256) {
        int k = i >> 4, c4 = (i & 15) * 4;
        float4 v = *reinterpret_cast<const float4*>(&W[(size_t)k * 64 + c4]);
        Wl[c4 + 0][k] = (unsigned short)f2bf(v.x);
        Wl[c4 + 1][k] = (unsigned short)f2bf(v.y);
        Wl[c4 + 2][k] = (unsigned short)f2bf(v.z);
        Wl[c4 + 3][k] = (unsigned short)f2bf(v.w);
    }
    __syncthreads();
    int wave = tid >> 6, lane = tid & 63;
    int m = lane & 15, g = lane >> 4;       // A-row within strip, k-group
    int row0 = blockIdx.x * 64 + wave * 16;
    int arow = row0 + m;
    bool aval = arow < N;
    const float* xr = x + (size_t)(aval ? arow : 0) * 512;
    float asw[4], adw[4];
    #pragma unroll
    for (int nt = 0; nt < 4; ++nt) {
        asw[nt] = a_src[nt * 16 + m];       // weight for output col nt*16+m
        adw[nt] = a_dst[nt * 16 + m];
    }
    f32x4 acc[4] = {{0.f,0.f,0.f,0.f},{0.f,0.f,0.f,0.f},{0.f,0.f,0.f,0.f},{0.f,0.f,0.f,0.f}};
    for (int kt = 0; kt < 512; kt += 32) {
        int ko = kt + g * 8;
        float4 u0 = make_float4(0.f, 0.f, 0.f, 0.f), u1 = u0;
        if (aval) {
            u0 = *reinterpret_cast<const float4*>(xr + ko);
            u1 = *reinterpret_cast<const float4*>(xr + ko + 4);
        }
        bf16x8 af;
        af[0] = (short)f2bf(u0.x); af[1] = (short)f2bf(u0.y);
        af[2] = (short)f2bf(u0.z); af[3] = (short)f2bf(u0.w);
        af[4] = (short)f2bf(u1.x); af[5] = (short)f2bf(u1.y);
        af[6] = (short)f2bf(u1.z); af[7] = (short)f2bf(u1.w);
        #pragma unroll
        for (int nt = 0; nt < 4; ++nt) {
            bf16x8 bf = *reinterpret_cast<const bf16x8*>(&Wl[nt * 16 + m][ko]);
            acc[nt] = __builtin_amdgcn_mfma_f32_16x16x32_bf16(af, bf, acc[nt], 0, 0, 0);
        }
    }
    // D layout: col = lane&15 (=m), row = g*4 + reg  [verified m89]
    #pragma unroll
    for (int r = 0; r < 4; ++r) {
        int orow = row0 + g * 4 + r;
        if (orow < N) {
            #pragma unroll
            for (int nt = 0; nt < 4; ++nt) {
                float dv = acc[nt][r];
                hb1[(size_t)orow * 64 + nt * 16 + m] = (unsigned short)f2bf(dv);
                float pa = dv * asw[nt];
                float pd = dv * adw[nt];
                pa += __shfl_xor(pa, 1); pa += __shfl_xor(pa, 2); pa += __shfl_xor(pa, 4);
                pd += __shfl_xor(pd, 1); pd += __shfl_xor(pd, 2); pd += __shfl_xor(pd, 4);
                if ((m & 7) == 0) {
                    as1[orow * 8 + nt * 2 + (m >> 3)] = pa;
                    ad1[orow * 8 + nt * 2 + (m >> 3)] = pd;
                }
            }
        }
    }
}

// ---- layer-1 attention: fused online softmax + aggregation (1 wave/dst, 4 edges/iter) ----

__global__ __launch_bounds__(256) void attn1_kernel(
    const unsigned short* __restrict__ hb1, const float* __restrict__ as1,
    const float* __restrict__ ad1, const int* __restrict__ rowptr,
    const int* __restrict__ csr_src, const float* __restrict__ b1,
    float* __restrict__ helu, int N) {
    int wv = threadIdx.x >> 6;
    int lane = threadIdx.x & 63;
    int d = blockIdx.x * 4 + wv;
    if (d >= N) return;
    int beg = rowptr[d];
    int edeg = rowptr[d + 1] - beg;
    int tot = edeg + 1;  // + virtual self loop (src = d)
    int q = lane & 15, g = lane >> 4, hh = q >> 1;
    float adh = ad1[d * 8 + hh];
    const uint2* hb = reinterpret_cast<const uint2*>(hb1);
    float m = -1e30f, s = 0.f, a0 = 0.f, a1 = 0.f, a2 = 0.f, a3 = 0.f;
    for (int p0 = 0; p0 < tot; p0 += 4) {
        int p = p0 + g;
        bool valid = p < tot;
        int sn = (p < edeg) ? csr_src[beg + p] : d;
        float e = as1[sn * 8 + hh] + adh;
        e = fmaxf(e, NEG_SLOPE * e);
        float nm = valid ? fmaxf(m, e) : m;
        float sc = __expf(m - nm);
        float w = valid ? __expf(e - nm) : 0.f;
        uint2 u = hb[(size_t)sn * 16 + q];
        float f0, f1, f2, f3;
        bf2x4(u, f0, f1, f2, f3);
        s = fmaf(s, sc, w);
        a0 = fmaf(a0, sc, w * f0);
        a1 = fmaf(a1, sc, w * f1);
        a2 = fmaf(a2, sc, w * f2);
        a3 = fmaf(a3, sc, w * f3);
        m = nm;
    }
    #pragma unroll
    for (int mask = 16; mask < 64; mask <<= 1) {
        float om = __shfl_xor(m, mask), os = __shfl_xor(s, mask);
        float o0 = __shfl_xor(a0, mask), o1 = __shfl_xor(a1, mask);
        float o2 = __shfl_xor(a2, mask), o3 = __shfl_xor(a3, mask);
        float nm = fmaxf(m, om);
        float x1 = __expf(m - nm), x2 = __expf(om - nm);
        s = s * x1 + os * x2;
        a0 = a0 * x1 + o0 * x2;
        a1 = a1 * x1 + o1 * x2;
        a2 = a2 * x1 + o2 * x2;
        a3 = a3 * x1 + o3 * x2;
        m = nm;
    }
    if (lane < 16) {
        float inv = 1.f / (s + 1e-16f);
        const float4 bv = *reinterpret_cast<const float4*>(&b1[q * 4]);
        float4 o;
        o.x = fmaf(a0, inv, bv.x);
        o.y = fmaf(a1, inv, bv.y);
        o.z = fmaf(a2, inv, bv.z);
        o.w = fmaf(a3, inv, bv.w);
        o.x = (o.x > 0.f) ? o.x : (__expf(o.x) - 1.f);
        o.y = (o.y > 0.f) ? o.y : (__expf(o.y) - 1.f);
        o.z = (o.z > 0.f) ? o.z : (__expf(o.z) - 1.f);
        o.w = (o.w > 0.f) ? o.w : (__expf(o.w) - 1.f);
        *reinterpret_cast<float4*>(&helu[(size_t)d * 64 + q * 4]) = o;
    }
}

// ---- GEMM2 (64x64) + alpha2, one wave per row; bf16 h2 out ----

__global__ __launch_bounds__(256) void gemm2_kernel(
    const float* __restrict__ helu, const float* __restrict__ W2,
    const float* __restrict__ a_src2, const float* __restrict__ a_dst2,
    unsigned short* __restrict__ hb2, float* __restrict__ as2, float* __restrict__ ad2, int N) {
    __shared__ float Ws[64 * 64];
    __shared__ float asw[64], adw[64];
    int tid = threadIdx.x;
    for (int i = tid; i < 64 * 64; i += 256) Ws[i] = W2[i];
    if (tid < 64) { asw[tid] = a_src2[tid]; adw[tid] = a_dst2[tid]; }
    __syncthreads();
    int lane = tid & 63, wv = tid >> 6;
    int stride = gridDim.x * 4;
    for (int row = blockIdx.x * 4 + wv; row < N; row += stride) {
        float hv = helu[(size_t)row * 64 + lane];
        float acc = 0.f;
        #pragma unroll
        for (int k = 0; k < 64; ++k) {
            float v = __shfl(hv, k);
            acc += v * Ws[k * 64 + lane];
        }
        hb2[(size_t)row * 64 + lane] = (unsigned short)f2bf(acc);
        float pa = acc * asw[lane];
        float pb = acc * adw[lane];
        #pragma unroll
        for (int mask = 1; mask < 64; mask <<= 1) {
            pa += __shfl_xor(pa, mask);
            pb += __shfl_xor(pb, mask);
        }
        if (lane == 0) { as2[row] = pa; ad2[row] = pb; }
    }
}

// ---- layer-2 attention + log_softmax (fused online softmax, 4 edges/iter) ----

__global__ __launch_bounds__(256) void attn2_kernel(
    const unsigned short* __restrict__ hb2, const float* __restrict__ as2,
    const float* __restrict__ ad2, const int* __restrict__ rowptr,
    const int* __restrict__ csr_src, const float* __restrict__ b2,
    float* __restrict__ out, int N) {
    int wv = threadIdx.x >> 6;
    int lane = threadIdx.x & 63;
    int d = blockIdx.x * 4 + wv;
    if (d >= N) return;
    int beg = rowptr[d];
    int edeg = rowptr[d + 1] - beg;
    int tot = edeg + 1;
    int q = lane & 15, g = lane >> 4;
    float add = ad2[d];
    const uint2* hb = reinterpret_cast<const uint2*>(hb2);
    float m = -1e30f, s = 0.f, a0 = 0.f, a1 = 0.f, a2 = 0.f, a3 = 0.f;
    for (int p0 = 0; p0 < tot; p0 += 4) {
        int p = p0 + g;
        bool valid = p < tot;
        int sn = (p < edeg) ? csr_src[beg + p] : d;
        float e = as2[sn] + add;
        e = fmaxf(e, NEG_SLOPE * e);
        float nm = valid ? fmaxf(m, e) : m;
        float sc = __expf(m - nm);
        float w = valid ? __expf(e - nm) : 0.f;
        uint2 u = hb[(size_t)sn * 16 + q];
        float f0, f1, f2, f3;
        bf2x4(u, f0, f1, f2, f3);
        s = fmaf(s, sc, w);
        a0 = fmaf(a0, sc, w * f0);
        a1 = fmaf(a1, sc, w * f1);
        a2 = fmaf(a2, sc, w * f2);
        a3 = fmaf(a3, sc, w * f3);
        m = nm;
    }
    #pragma unroll
    for (int mask = 16; mask < 64; mask <<= 1) {
        float om = __shfl_xor(m, mask), os = __shfl_xor(s, mask);
        float o0 = __shfl_xor(a0, mask), o1 = __shfl_xor(a1, mask);
        float o2 = __shfl_xor(a2, mask), o3 = __shfl_xor(a3, mask);
        float nm = fmaxf(m, om);
        float x1 = __expf(m - nm), x2 = __expf(om - nm);
        s = s * x1 + os * x2;
        a0 = a0 * x1 + o0 * x2;
        a1 = a1 * x1 + o1 * x2;
        a2 = a2 * x1 + o2 * x2;
        a3 = a3 * x1 + o3 * x2;
        m = nm;
    }
    float inv = 1.f / (s + 1e-16f);
    const float4 bv = *reinterpret_cast<const float4*>(&b2[q * 4]);
    float o0 = fmaf(a0, inv, bv.x);
    float o1 = fmaf(a1, inv, bv.y);
    float o2 = fmaf(a2, inv, bv.z);
    float o3 = fmaf(a3, inv, bv.w);
    float mx = fmaxf(fmaxf(o0, o1), fmaxf(o2, o3));
    #pragma unroll
    for (int mask = 1; mask < 16; mask <<= 1) mx = fmaxf(mx, __shfl_xor(mx, mask));
    float sm = __expf(o0 - mx) + __expf(o1 - mx) + __expf(o2 - mx) + __expf(o3 - mx);
    #pragma unroll
    for (int mask = 1; mask < 16; mask <<= 1) sm += __shfl_xor(sm, mask);
    float lse = mx + __logf(sm);
    if (lane < 16) {
        float4 o;
        o.x = o0 - lse; o.y = o1 - lse; o.z = o2 - lse; o.w = o3 - lse;
        *reinterpret_cast<float4*>(&out[(size_t)d * 64 + q * 4]) = o;
    }
}

// ---------------- launch ----------------

extern "C" void kernel_launch(void* const* d_in, const int* in_sizes, int n_in,
                              void* d_out, int out_size, void* d_ws, size_t ws_size,
                              hipStream_t stream) {
    const float* x      = (const float*)d_in[0];
    const int*   ei     = (const int*)d_in[1];
    const float* W1     = (const float*)d_in[2];
    const float* a_src1 = (const float*)d_in[3];
    const float* a_dst1 = (const float*)d_in[4];
    const float* b1     = (const float*)d_in[5];
    const float* W2     = (const float*)d_in[6];
    const float* a_src2 = (const float*)d_in[7];
    const float* a_dst2 = (const float*)d_in[8];
    const float* b2     = (const float*)d_in[9];

    int N = in_sizes[0] / 512;
    int E = in_sizes[1] / 2;
    const int* src = ei;
    const int* dst = ei + E;
    int NB = (N + 255) >> NB_SHIFT;          // 391 buckets of 256 nodes

    char* w = (char*)d_ws;
    size_t off = 0;
    auto alloc = [&](size_t bytes) -> void* {
        off = (off + 255) & ~(size_t)255;
        void* p = w + off;
        off += bytes;
        return p;
    };
    int* bcnt   = (int*)alloc((size_t)NB * sizeof(int));
    int* rowptr = (int*)alloc((size_t)(N + 1) * sizeof(int));
    int* bbase  = (int*)alloc((size_t)(NB + 1) * sizeof(int));
    int* bcur   = (int*)alloc((size_t)NB * sizeof(int));
    int* csr    = (int*)alloc((size_t)E * sizeof(int));
    unsigned short* hb1 = (unsigned short*)alloc((size_t)N * 64 * sizeof(unsigned short));
    float* as1  = (float*)alloc((size_t)N * 8 * sizeof(float));
    float* ad1  = (float*)alloc((size_t)N * 8 * sizeof(float));
    float* helu = (float*)alloc((size_t)N * 64 * sizeof(float));
    uint2* pairs = (uint2*)helu;             // alias: pairs dead before attn1 writes helu
    unsigned short* hb2 = hb1;               // aliases: hb1/as1/ad1 dead after attn1
    float* as2 = as1;
    float* ad2 = ad1;

    zero_int_kernel<<<(NB + 255) / 256, 256, 0, stream>>>(bcnt, NB);
    bucket_count_kernel<<<(E + 16383) / 16384, 256, 0, stream>>>(dst, E, bcnt, NB);
    scan_bucket_kernel<<<1, 512, 0, stream>>>(bcnt, NB, bbase, bcur, rowptr, N);
    bucket_scatter_kernel<<<(E + 8191) / 8192, 256, 0, stream>>>(src, dst, E, bcur, pairs, NB);
    build_csr_kernel<<<NB, 512, 0, stream>>>(pairs, bbase, rowptr, csr, N);

    gemm1_kernel<<<(N + 63) / 64, 256, 0, stream>>>(x, W1, a_src1, a_dst1, hb1, as1, ad1, N);
    attn1_kernel<<<(N + 3) / 4, 256, 0, stream>>>(hb1, as1, ad1, rowptr, csr, b1, helu, N);

    gemm2_kernel<<<2048, 256, 0, stream>>>(helu, W2, a_src2, a_dst2, hb2, as2, ad2, N);
    attn2_kernel<<<(N + 3) / 4, 256, 0, stream>>>(hb2, as2, ad2, rowptr, csr, b2, (float*)d_out, N);
}

// Round 8
// 465.271 us; speedup vs baseline: 2.9268x; 1.0603x over previous
//
#include <hip/hip_runtime.h>

#define NEG_SLOPE 0.2f
#define NB_SHIFT 8          // bucket = dst >> 8 (256-node windows)

typedef __attribute__((ext_vector_type(8))) short bf16x8;
typedef __attribute__((ext_vector_type(4))) float f32x4;

// bf16 helpers (RNE pack, cheap unpack)
__device__ inline unsigned f2bf(float f) {
    unsigned u = __float_as_uint(f);
    return (u + 0x7fffu + ((u >> 16) & 1u)) >> 16;
}
__device__ inline void bf2x4(uint2 u, float& f0, float& f1, float& f2, float& f3) {
    f0 = __uint_as_float(u.x << 16);
    f1 = __uint_as_float(u.x & 0xffff0000u);
    f2 = __uint_as_float(u.y << 16);
    f3 = __uint_as_float(u.y & 0xffff0000u);
}

// ---------------- CSR build (no per-edge global atomics) ----------------

__global__ void zero_int_kernel(int* __restrict__ p, int n) {
    int i = blockIdx.x * blockDim.x + threadIdx.x;
    if (i < n) p[i] = 0;
}

// bucket histogram only: LDS counters, one global atomic per bucket per block
__global__ __launch_bounds__(256) void bucket_count_kernel(const int* __restrict__ dst, int E,
                                                           int* __restrict__ bcnt, int NB) {
    __shared__ int cnt[512];
    for (int i = threadIdx.x; i < NB; i += 256) cnt[i] = 0;
    __syncthreads();
    int base = blockIdx.x * 16384;
    for (int k = 0; k < 64; ++k) {
        int i = base + k * 256 + threadIdx.x;
        if (i < E) atomicAdd(&cnt[dst[i] >> NB_SHIFT], 1);
    }
    __syncthreads();
    for (int i = threadIdx.x; i < NB; i += 256)
        if (cnt[i]) atomicAdd(&bcnt[i], cnt[i]);
}

// single 512-thread block: exclusive scan of bcnt[NB] -> bbase (+bcur copy); bbase[NB]=rowptr[N]=E
__global__ __launch_bounds__(512) void scan_bucket_kernel(const int* __restrict__ bcnt, int nb,
                                                          int* __restrict__ bbase,
                                                          int* __restrict__ bcur,
                                                          int* __restrict__ rowptr, int N) {
    int t = threadIdx.x;
    int v = (t < nb) ? bcnt[t] : 0;
    int s = v;
    #pragma unroll
    for (int d = 1; d < 64; d <<= 1) {
        int o = __shfl_up(s, d);
        if ((t & 63) >= d) s += o;
    }
    __shared__ int ws[8];
    if ((t & 63) == 63) ws[t >> 6] = s;
    __syncthreads();
    int wid = t >> 6;
    int woff = 0;
    for (int w = 0; w < 8; ++w) woff += (w < wid) ? ws[w] : 0;
    int excl = s - v + woff;
    if (t < nb) { bbase[t] = excl; bcur[t] = excl; }
    if (t == 511) { bbase[nb] = excl + v; rowptr[N] = excl + v; }  // grand total = E
}

// scatter (src,dst) pairs into bucket-grouped storage, LDS-rank aggregated; 8192 edges/block
__global__ __launch_bounds__(256) void bucket_scatter_kernel(const int* __restrict__ src,
                                                             const int* __restrict__ dst, int E,
                                                             int* __restrict__ bcur,
                                                             uint2* __restrict__ pairs, int NB) {
    __shared__ int cnt[512];
    __shared__ int base_l[512];
    for (int i = threadIdx.x; i < NB; i += 256) cnt[i] = 0;
    __syncthreads();
    int tbase = blockIdx.x * 8192;
    uint2 e[32];
    int rk[32];
    #pragma unroll
    for (int k = 0; k < 32; ++k) {
        int i = tbase + k * 256 + threadIdx.x;
        if (i < E) {
            e[k].x = (unsigned)src[i];
            e[k].y = (unsigned)dst[i];
            rk[k] = atomicAdd(&cnt[e[k].y >> NB_SHIFT], 1);
        } else {
            rk[k] = -1;
        }
    }
    __syncthreads();
    for (int i = threadIdx.x; i < NB; i += 256)
        base_l[i] = cnt[i] ? atomicAdd(&bcur[i], cnt[i]) : 0;
    __syncthreads();
    #pragma unroll
    for (int k = 0; k < 32; ++k)
        if (rk[k] >= 0) pairs[base_l[e[k].y >> NB_SHIFT] + rk[k]] = e[k];
}

// one block per bucket: LDS degree count -> local scan -> rowptr write -> LDS-cursor place
__global__ __launch_bounds__(512) void build_csr_kernel(const uint2* __restrict__ pairs,
                                                        const int* __restrict__ bbase,
                                                        int* __restrict__ rowptr,
                                                        int* __restrict__ csr, int N) {
    __shared__ int cnt[256];
    __shared__ int cur[256];
    __shared__ int ws[4];
    int b = blockIdx.x;
    int lo = bbase[b], hi = bbase[b + 1];
    int t = threadIdx.x;
    if (t < 256) cnt[t] = 0;
    __syncthreads();
    for (int j = lo + t; j < hi; j += 512)
        atomicAdd(&cnt[pairs[j].y & 255], 1);
    __syncthreads();
    int v = 0, s = 0;
    if (t < 256) {
        v = cnt[t];
        s = v;
        #pragma unroll
        for (int d = 1; d < 64; d <<= 1) {
            int o = __shfl_up(s, d);
            if ((t & 63) >= d) s += o;
        }
        if ((t & 63) == 63) ws[t >> 6] = s;
    }
    __syncthreads();
    if (t < 256) {
        int wid = t >> 6;
        int woff = 0;
        for (int w2 = 0; w2 < 4; ++w2) woff += (w2 < wid) ? ws[w2] : 0;
        int excl = lo + s - v + woff;
        int node = (b << NB_SHIFT) + t;
        if (node < N) rowptr[node] = excl;
        cur[t] = excl;
    }
    __syncthreads();
    for (int j = lo + t; j < hi; j += 512) {
        uint2 p = pairs[j];
        int pos = atomicAdd(&cur[p.y & 255], 1);   // LDS atomic
        csr[pos] = (int)p.x;
    }
}

// ---- GEMM1 (MFMA bf16): hb1 = bf16(x @ W1), fused as1/ad1 epilogue ----
// W1 staged to LDS in FRAGMENT ORDER [kstep][ntile][lane][8 bf16]: each wave's
// ds_read_b128 is 64 lanes x consecutive 16B = contiguous 1KB, zero conflicts.
// 8 waves/block, each owns a 16-row strip (128 rows/block); K=512, 16 steps of 32.

__global__ __launch_bounds__(512) void gemm1_kernel(const float* __restrict__ x,
                                                    const float* __restrict__ W,
                                                    const float* __restrict__ a_src,
                                                    const float* __restrict__ a_dst,
                                                    unsigned short* __restrict__ hb1,
                                                    float* __restrict__ as1,
                                                    float* __restrict__ ad1, int N) {
    __shared__ unsigned short Wl[16 * 4 * 64 * 8];   // 64 KB, fragment-ordered
    int tid = threadIdx.x;
    for (int i = tid; i < 512 * 16; i += 512) {
        int k = i >> 4, c4 = (i & 15) * 4;
        float4 v = *reinterpret_cast<const float4*>(&W[(size_t)k * 64 + c4]);
        int ks = k >> 5, kin = k & 31, g = kin >> 3, j = kin & 7;
        float vv[4] = {v.x, v.y, v.z, v.w};
        #pragma unroll
        for (int c = 0; c < 4; ++c) {
            int col = c4 + c;
            int nt = col >> 4, l16 = col & 15;
            Wl[(((ks * 4 + nt) * 64) + g * 16 + l16) * 8 + j] = (unsigned short)f2bf(vv[c]);
        }
    }
    __syncthreads();
    int wave = tid >> 6, lane = tid & 63;
    int m = lane & 15, g = lane >> 4;       // A-row within strip, k-group
    int row0 = blockIdx.x * 128 + wave * 16;
    int arow = row0 + m;
    bool aval = arow < N;
    const float* xr = x + (size_t)(aval ? arow : 0) * 512;
    float asw[4], adw[4];
    #pragma unroll
    for (int nt = 0; nt < 4; ++nt) {
        asw[nt] = a_src[nt * 16 + m];       // weight for output col nt*16+m
        adw[nt] = a_dst[nt * 16 + m];
    }
    f32x4 acc[4] = {{0.f,0.f,0.f,0.f},{0.f,0.f,0.f,0.f},{0.f,0.f,0.f,0.f},{0.f,0.f,0.f,0.f}};
    for (int ks = 0; ks < 16; ++ks) {
        int ko = ks * 32 + g * 8;
        float4 u0 = make_float4(0.f, 0.f, 0.f, 0.f), u1 = u0;
        if (aval) {
            u0 = *reinterpret_cast<const float4*>(xr + ko);
            u1 = *reinterpret_cast<const float4*>(xr + ko + 4);
        }
        bf16x8 af;
        af[0] = (short)f2bf(u0.x); af[1] = (short)f2bf(u0.y);
        af[2] = (short)f2bf(u0.z); af[3] = (short)f2bf(u0.w);
        af[4] = (short)f2bf(u1.x); af[5] = (short)f2bf(u1.y);
        af[6] = (short)f2bf(u1.z); af[7] = (short)f2bf(u1.w);
        #pragma unroll
        for (int nt = 0; nt < 4; ++nt) {
            bf16x8 bf = *reinterpret_cast<const bf16x8*>(&Wl[((ks * 4 + nt) * 64 + lane) * 8]);
            acc[nt] = __builtin_amdgcn_mfma_f32_16x16x32_bf16(af, bf, acc[nt], 0, 0, 0);
        }
    }
    // D layout: col = lane&15 (=m), row = g*4 + reg  [verified m89]
    #pragma unroll
    for (int r = 0; r < 4; ++r) {
        int orow = row0 + g * 4 + r;
        if (orow < N) {
            #pragma unroll
            for (int nt = 0; nt < 4; ++nt) {
                float dv = acc[nt][r];
                hb1[(size_t)orow * 64 + nt * 16 + m] = (unsigned short)f2bf(dv);
                float pa = dv * asw[nt];
                float pd = dv * adw[nt];
                pa += __shfl_xor(pa, 1); pa += __shfl_xor(pa, 2); pa += __shfl_xor(pa, 4);
                pd += __shfl_xor(pd, 1); pd += __shfl_xor(pd, 2); pd += __shfl_xor(pd, 4);
                if ((m & 7) == 0) {
                    as1[orow * 8 + nt * 2 + (m >> 3)] = pa;
                    ad1[orow * 8 + nt * 2 + (m >> 3)] = pd;
                }
            }
        }
    }
}

// ---- layer-1 attention: fused online softmax + aggregation (1 wave/dst, 4 edges/iter) ----

__global__ __launch_bounds__(256) void attn1_kernel(
    const unsigned short* __restrict__ hb1, const float* __restrict__ as1,
    const float* __restrict__ ad1, const int* __restrict__ rowptr,
    const int* __restrict__ csr_src, const float* __restrict__ b1,
    float* __restrict__ helu, int N) {
    int wv = threadIdx.x >> 6;
    int lane = threadIdx.x & 63;
    int d = blockIdx.x * 4 + wv;
    if (d >= N) return;
    int beg = rowptr[d];
    int edeg = rowptr[d + 1] - beg;
    int tot = edeg + 1;  // + virtual self loop (src = d)
    int q = lane & 15, g = lane >> 4, hh = q >> 1;
    float adh = ad1[d * 8 + hh];
    const uint2* hb = reinterpret_cast<const uint2*>(hb1);
    float m = -1e30f, s = 0.f, a0 = 0.f, a1 = 0.f, a2 = 0.f, a3 = 0.f;
    for (int p0 = 0; p0 < tot; p0 += 4) {
        int p = p0 + g;
        bool valid = p < tot;
        int sn = (p < edeg) ? csr_src[beg + p] : d;
        float e = as1[sn * 8 + hh] + adh;
        e = fmaxf(e, NEG_SLOPE * e);
        float nm = valid ? fmaxf(m, e) : m;
        float sc = __expf(m - nm);
        float w = valid ? __expf(e - nm) : 0.f;
        uint2 u = hb[(size_t)sn * 16 + q];
        float f0, f1, f2, f3;
        bf2x4(u, f0, f1, f2, f3);
        s = fmaf(s, sc, w);
        a0 = fmaf(a0, sc, w * f0);
        a1 = fmaf(a1, sc, w * f1);
        a2 = fmaf(a2, sc, w * f2);
        a3 = fmaf(a3, sc, w * f3);
        m = nm;
    }
    #pragma unroll
    for (int mask = 16; mask < 64; mask <<= 1) {
        float om = __shfl_xor(m, mask), os = __shfl_xor(s, mask);
        float o0 = __shfl_xor(a0, mask), o1 = __shfl_xor(a1, mask);
        float o2 = __shfl_xor(a2, mask), o3 = __shfl_xor(a3, mask);
        float nm = fmaxf(m, om);
        float x1 = __expf(m - nm), x2 = __expf(om - nm);
        s = s * x1 + os * x2;
        a0 = a0 * x1 + o0 * x2;
        a1 = a1 * x1 + o1 * x2;
        a2 = a2 * x1 + o2 * x2;
        a3 = a3 * x1 + o3 * x2;
        m = nm;
    }
    if (lane < 16) {
        float inv = 1.f / (s + 1e-16f);
        const float4 bv = *reinterpret_cast<const float4*>(&b1[q * 4]);
        float4 o;
        o.x = fmaf(a0, inv, bv.x);
        o.y = fmaf(a1, inv, bv.y);
        o.z = fmaf(a2, inv, bv.z);
        o.w = fmaf(a3, inv, bv.w);
        o.x = (o.x > 0.f) ? o.x : (__expf(o.x) - 1.f);
        o.y = (o.y > 0.f) ? o.y : (__expf(o.y) - 1.f);
        o.z = (o.z > 0.f) ? o.z : (__expf(o.z) - 1.f);
        o.w = (o.w > 0.f) ? o.w : (__expf(o.w) - 1.f);
        *reinterpret_cast<float4*>(&helu[(size_t)d * 64 + q * 4]) = o;
    }
}

// ---- GEMM2 (64x64) + alpha2, one wave per row; bf16 h2 out ----

__global__ __launch_bounds__(256) void gemm2_kernel(
    const float* __restrict__ helu, const float* __restrict__ W2,
    const float* __restrict__ a_src2, const float* __restrict__ a_dst2,
    unsigned short* __restrict__ hb2, float* __restrict__ as2, float* __restrict__ ad2, int N) {
    __shared__ float Ws[64 * 64];
    __shared__ float asw[64], adw[64];
    int tid = threadIdx.x;
    for (int i = tid; i < 64 * 64; i += 256) Ws[i] = W2[i];
    if (tid < 64) { asw[tid] = a_src2[tid]; adw[tid] = a_dst2[tid]; }
    __syncthreads();
    int lane = tid & 63, wv = tid >> 6;
    int stride = gridDim.x * 4;
    for (int row = blockIdx.x * 4 + wv; row < N; row += stride) {
        float hv = helu[(size_t)row * 64 + lane];
        float acc = 0.f;
        #pragma unroll
        for (int k = 0; k < 64; ++k) {
            float v = __shfl(hv, k);
            acc += v * Ws[k * 64 + lane];
        }
        hb2[(size_t)row * 64 + lane] = (unsigned short)f2bf(acc);
        float pa = acc * asw[lane];
        float pb = acc * adw[lane];
        #pragma unroll
        for (int mask = 1; mask < 64; mask <<= 1) {
            pa += __shfl_xor(pa, mask);
            pb += __shfl_xor(pb, mask);
        }
        if (lane == 0) { as2[row] = pa; ad2[row] = pb; }
    }
}

// ---- layer-2 attention + log_softmax (fused online softmax, 4 edges/iter) ----

__global__ __launch_bounds__(256) void attn2_kernel(
    const unsigned short* __restrict__ hb2, const float* __restrict__ as2,
    const float* __restrict__ ad2, const int* __restrict__ rowptr,
    const int* __restrict__ csr_src, const float* __restrict__ b2,
    float* __restrict__ out, int N) {
    int wv = threadIdx.x >> 6;
    int lane = threadIdx.x & 63;
    int d = blockIdx.x * 4 + wv;
    if (d >= N) return;
    int beg = rowptr[d];
    int edeg = rowptr[d + 1] - beg;
    int tot = edeg + 1;
    int q = lane & 15, g = lane >> 4;
    float add = ad2[d];
    const uint2* hb = reinterpret_cast<const uint2*>(hb2);
    float m = -1e30f, s = 0.f, a0 = 0.f, a1 = 0.f, a2 = 0.f, a3 = 0.f;
    for (int p0 = 0; p0 < tot; p0 += 4) {
        int p = p0 + g;
        bool valid = p < tot;
        int sn = (p < edeg) ? csr_src[beg + p] : d;
        float e = as2[sn] + add;
        e = fmaxf(e, NEG_SLOPE * e);
        float nm = valid ? fmaxf(m, e) : m;
        float sc = __expf(m - nm);
        float w = valid ? __expf(e - nm) : 0.f;
        uint2 u = hb[(size_t)sn * 16 + q];
        float f0, f1, f2, f3;
        bf2x4(u, f0, f1, f2, f3);
        s = fmaf(s, sc, w);
        a0 = fmaf(a0, sc, w * f0);
        a1 = fmaf(a1, sc, w * f1);
        a2 = fmaf(a2, sc, w * f2);
        a3 = fmaf(a3, sc, w * f3);
        m = nm;
    }
    #pragma unroll
    for (int mask = 16; mask < 64; mask <<= 1) {
        float om = __shfl_xor(m, mask), os = __shfl_xor(s, mask);
        float o0 = __shfl_xor(a0, mask), o1 = __shfl_xor(a1, mask);
        float o2 = __shfl_xor(a2, mask), o3 = __shfl_xor(a3, mask);
        float nm = fmaxf(m, om);
        float x1 = __expf(m - nm), x2 = __expf(om - nm);
        s = s * x1 + os * x2;
        a0 = a0 * x1 + o0 * x2;
        a1 = a1 * x1 + o1 * x2;
        a2 = a2 * x1 + o2 * x2;
        a3 = a3 * x1 + o3 * x2;
        m = nm;
    }
    float inv = 1.f / (s + 1e-16f);
    const float4 bv = *reinterpret_cast<const float4*>(&b2[q * 4]);
    float o0 = fmaf(a0, inv, bv.x);
    float o1 = fmaf(a1, inv, bv.y);
    float o2 = fmaf(a2, inv, bv.z);
    float o3 = fmaf(a3, inv, bv.w);
    float mx = fmaxf(fmaxf(o0, o1), fmaxf(o2, o3));
    #pragma unroll
    for (int mask = 1; mask < 16; mask <<= 1) mx = fmaxf(mx, __shfl_xor(mx, mask));
    float sm = __expf(o0 - mx) + __expf(o1 - mx) + __expf(o2 - mx) + __expf(o3 - mx);
    #pragma unroll
    for (int mask = 1; mask < 16; mask <<= 1) sm += __shfl_xor(sm, mask);
    float lse = mx + __logf(sm);
    if (lane < 16) {
        float4 o;
        o.x = o0 - lse; o.y = o1 - lse; o.z = o2 - lse; o.w = o3 - lse;
        *reinterpret_cast<float4*>(&out[(size_t)d * 64 + q * 4]) = o;
    }
}

// ---------------- launch ----------------

extern "C" void kernel_launch(void* const* d_in, const int* in_sizes, int n_in,
                              void* d_out, int out_size, void* d_ws, size_t ws_size,
                              hipStream_t stream) {
    const float* x      = (const float*)d_in[0];
    const int*   ei     = (const int*)d_in[1];
    const float* W1     = (const float*)d_in[2];
    const float* a_src1 = (const float*)d_in[3];
    const float* a_dst1 = (const float*)d_in[4];
    const float* b1     = (const float*)d_in[5];
    const float* W2     = (const float*)d_in[6];
    const float* a_src2 = (const float*)d_in[7];
    const float* a_dst2 = (const float*)d_in[8];
    const float* b2     = (const float*)d_in[9];

    int N = in_sizes[0] / 512;
    int E = in_sizes[1] / 2;
    const int* src = ei;
    const int* dst = ei + E;
    int NB = (N + 255) >> NB_SHIFT;          // 391 buckets of 256 nodes

    char* w = (char*)d_ws;
    size_t off = 0;
    auto alloc = [&](size_t bytes) -> void* {
        off = (off + 255) & ~(size_t)255;
        void* p = w + off;
        off += bytes;
        return p;
    };
    int* bcnt   = (int*)alloc((size_t)NB * sizeof(int));
    int* rowptr = (int*)alloc((size_t)(N + 1) * sizeof(int));
    int* bbase  = (int*)alloc((size_t)(NB + 1) * sizeof(int));
    int* bcur   = (int*)alloc((size_t)NB * sizeof(int));
    int* csr    = (int*)alloc((size_t)E * sizeof(int));
    unsigned short* hb1 = (unsigned short*)alloc((size_t)N * 64 * sizeof(unsigned short));
    float* as1  = (float*)alloc((size_t)N * 8 * sizeof(float));
    float* ad1  = (float*)alloc((size_t)N * 8 * sizeof(float));
    float* helu = (float*)alloc((size_t)N * 64 * sizeof(float));
    uint2* pairs = (uint2*)helu;             // alias: pairs dead before attn1 writes helu
    unsigned short* hb2 = hb1;               // aliases: hb1/as1/ad1 dead after attn1
    float* as2 = as1;
    float* ad2 = ad1;

    zero_int_kernel<<<(NB + 255) / 256, 256, 0, stream>>>(bcnt, NB);
    bucket_count_kernel<<<(E + 16383) / 16384, 256, 0, stream>>>(dst, E, bcnt, NB);
    scan_bucket_kernel<<<1, 512, 0, stream>>>(bcnt, NB, bbase, bcur, rowptr, N);
    bucket_scatter_kernel<<<(E + 8191) / 8192, 256, 0, stream>>>(src, dst, E, bcur, pairs, NB);
    build_csr_kernel<<<NB, 512, 0, stream>>>(pairs, bbase, rowptr, csr, N);

    gemm1_kernel<<<(N + 127) / 128, 512, 0, stream>>>(x, W1, a_src1, a_dst1, hb1, as1, ad1, N);
    attn1_kernel<<<(N + 3) / 4, 256, 0, stream>>>(hb1, as1, ad1, rowptr, csr, b1, helu, N);

    gemm2_kernel<<<2048, 256, 0, stream>>>(helu, W2, a_src2, a_dst2, hb2, as2, ad2, N);
    attn2_kernel<<<(N + 3) / 4, 256, 0, stream>>>(hb2, as2, ad2, rowptr, csr, b2, (float*)d_out, N);
}

// Round 10
// 409.445 us; speedup vs baseline: 3.3259x; 1.1363x over previous
//
#include <hip/hip_runtime.h>

#define NEG_SLOPE 0.2f
#define NB_SHIFT 8          // bucket = dst >> 8 (256-node windows)
#define LOG2E 1.4426950408889634f

typedef __attribute__((ext_vector_type(8))) short bf16x8;
typedef __attribute__((ext_vector_type(4))) float f32x4;

// bf16 helpers (RNE pack, cheap unpack)
__device__ inline unsigned f2bf(float f) {
    unsigned u = __float_as_uint(f);
    return (u + 0x7fffu + ((u >> 16) & 1u)) >> 16;
}
__device__ inline void bf8up(uint4 u, float* f) {
    f[0] = __uint_as_float(u.x << 16); f[1] = __uint_as_float(u.x & 0xffff0000u);
    f[2] = __uint_as_float(u.y << 16); f[3] = __uint_as_float(u.y & 0xffff0000u);
    f[4] = __uint_as_float(u.z << 16); f[5] = __uint_as_float(u.z & 0xffff0000u);
    f[6] = __uint_as_float(u.w << 16); f[7] = __uint_as_float(u.w & 0xffff0000u);
}
__device__ inline float exp2fast(float x) { return __builtin_amdgcn_exp2f(x); }

// ---------------- CSR build (no per-edge global atomics) ----------------

__global__ void zero_int_kernel(int* __restrict__ p, int n) {
    int i = blockIdx.x * blockDim.x + threadIdx.x;
    if (i < n) p[i] = 0;
}

__global__ __launch_bounds__(256) void bucket_count_kernel(const int* __restrict__ dst, int E,
                                                           int* __restrict__ bcnt, int NB) {
    __shared__ int cnt[512];
    for (int i = threadIdx.x; i < NB; i += 256) cnt[i] = 0;
    __syncthreads();
    int base = blockIdx.x * 16384;
    for (int k = 0; k < 64; ++k) {
        int i = base + k * 256 + threadIdx.x;
        if (i < E) atomicAdd(&cnt[dst[i] >> NB_SHIFT], 1);
    }
    __syncthreads();
    for (int i = threadIdx.x; i < NB; i += 256)
        if (cnt[i]) atomicAdd(&bcnt[i], cnt[i]);
}

__global__ __launch_bounds__(512) void scan_bucket_kernel(const int* __restrict__ bcnt, int nb,
                                                          int* __restrict__ bbase,
                                                          int* __restrict__ bcur,
                                                          int* __restrict__ rowptr, int N) {
    int t = threadIdx.x;
    int v = (t < nb) ? bcnt[t] : 0;
    int s = v;
    #pragma unroll
    for (int d = 1; d < 64; d <<= 1) {
        int o = __shfl_up(s, d);
        if ((t & 63) >= d) s += o;
    }
    __shared__ int ws[8];
    if ((t & 63) == 63) ws[t >> 6] = s;
    __syncthreads();
    int wid = t >> 6;
    int woff = 0;
    for (int w = 0; w < 8; ++w) woff += (w < wid) ? ws[w] : 0;
    int excl = s - v + woff;
    if (t < nb) { bbase[t] = excl; bcur[t] = excl; }
    if (t == 511) { bbase[nb] = excl + v; rowptr[N] = excl + v; }  // grand total = E
}

__global__ __launch_bounds__(256) void bucket_scatter_kernel(const int* __restrict__ src,
                                                             const int* __restrict__ dst, int E,
                                                             int* __restrict__ bcur,
                                                             uint2* __restrict__ pairs, int NB) {
    __shared__ int cnt[512];
    __shared__ int base_l[512];
    for (int i = threadIdx.x; i < NB; i += 256) cnt[i] = 0;
    __syncthreads();
    int tbase = blockIdx.x * 8192;
    uint2 e[32];
    int rk[32];
    #pragma unroll
    for (int k = 0; k < 32; ++k) {
        int i = tbase + k * 256 + threadIdx.x;
        if (i < E) {
            e[k].x = (unsigned)src[i];
            e[k].y = (unsigned)dst[i];
            rk[k] = atomicAdd(&cnt[e[k].y >> NB_SHIFT], 1);
        } else {
            rk[k] = -1;
        }
    }
    __syncthreads();
    for (int i = threadIdx.x; i < NB; i += 256)
        base_l[i] = cnt[i] ? atomicAdd(&bcur[i], cnt[i]) : 0;
    __syncthreads();
    #pragma unroll
    for (int k = 0; k < 32; ++k)
        if (rk[k] >= 0) pairs[base_l[e[k].y >> NB_SHIFT] + rk[k]] = e[k];
}

__global__ __launch_bounds__(512) void build_csr_kernel(const uint2* __restrict__ pairs,
                                                        const int* __restrict__ bbase,
                                                        int* __restrict__ rowptr,
                                                        int* __restrict__ csr, int N) {
    __shared__ int cnt[256];
    __shared__ int cur[256];
    __shared__ int ws[4];
    int b = blockIdx.x;
    int lo = bbase[b], hi = bbase[b + 1];
    int t = threadIdx.x;
    if (t < 256) cnt[t] = 0;
    __syncthreads();
    for (int j = lo + t; j < hi; j += 512)
        atomicAdd(&cnt[pairs[j].y & 255], 1);
    __syncthreads();
    int v = 0, s = 0;
    if (t < 256) {
        v = cnt[t];
        s = v;
        #pragma unroll
        for (int d = 1; d < 64; d <<= 1) {
            int o = __shfl_up(s, d);
            if ((t & 63) >= d) s += o;
        }
        if ((t & 63) == 63) ws[t >> 6] = s;
    }
    __syncthreads();
    if (t < 256) {
        int wid = t >> 6;
        int woff = 0;
        for (int w2 = 0; w2 < 4; ++w2) woff += (w2 < wid) ? ws[w2] : 0;
        int excl = lo + s - v + woff;
        int node = (b << NB_SHIFT) + t;
        if (node < N) rowptr[node] = excl;
        cur[t] = excl;
    }
    __syncthreads();
    for (int j = lo + t; j < hi; j += 512) {
        uint2 p = pairs[j];
        int pos = atomicAdd(&cur[p.y & 255], 1);   // LDS atomic
        csr[pos] = (int)p.x;
    }
}

// ---- GEMM1 (MFMA bf16): hb1 = bf16(x @ W1), fused as1/ad1 epilogue ----
// as1/ad1 pre-scaled by LOG2E (attention exps become bare exp2).

__global__ __launch_bounds__(512) void gemm1_kernel(const float* __restrict__ x,
                                                    const float* __restrict__ W,
                                                    const float* __restrict__ a_src,
                                                    const float* __restrict__ a_dst,
                                                    unsigned short* __restrict__ hb1,
                                                    float* __restrict__ as1,
                                                    float* __restrict__ ad1, int N) {
    __shared__ unsigned short Wl[16 * 4 * 64 * 8];   // 64 KB, fragment-ordered
    int tid = threadIdx.x;
    for (int i = tid; i < 512 * 16; i += 512) {
        int k = i >> 4, c4 = (i & 15) * 4;
        float4 v = *reinterpret_cast<const float4*>(&W[(size_t)k * 64 + c4]);
        int ks = k >> 5, kin = k & 31, g = kin >> 3, j = kin & 7;
        float vv[4] = {v.x, v.y, v.z, v.w};
        #pragma unroll
        for (int c = 0; c < 4; ++c) {
            int col = c4 + c;
            int nt = col >> 4, l16 = col & 15;
            Wl[(((ks * 4 + nt) * 64) + g * 16 + l16) * 8 + j] = (unsigned short)f2bf(vv[c]);
        }
    }
    __syncthreads();
    int wave = tid >> 6, lane = tid & 63;
    int m = lane & 15, g = lane >> 4;       // A-row within strip, k-group
    int row0 = blockIdx.x * 128 + wave * 16;
    int arow = row0 + m;
    bool aval = arow < N;
    const float* xr = x + (size_t)(aval ? arow : 0) * 512;
    float asw[4], adw[4];
    #pragma unroll
    for (int nt = 0; nt < 4; ++nt) {
        asw[nt] = a_src[nt * 16 + m] * LOG2E;
        adw[nt] = a_dst[nt * 16 + m] * LOG2E;
    }
    f32x4 acc[4] = {{0.f,0.f,0.f,0.f},{0.f,0.f,0.f,0.f},{0.f,0.f,0.f,0.f},{0.f,0.f,0.f,0.f}};
    for (int ks = 0; ks < 16; ++ks) {
        int ko = ks * 32 + g * 8;
        float4 u0 = make_float4(0.f, 0.f, 0.f, 0.f), u1 = u0;
        if (aval) {
            u0 = *reinterpret_cast<const float4*>(xr + ko);
            u1 = *reinterpret_cast<const float4*>(xr + ko + 4);
        }
        bf16x8 af;
        af[0] = (short)f2bf(u0.x); af[1] = (short)f2bf(u0.y);
        af[2] = (short)f2bf(u0.z); af[3] = (short)f2bf(u0.w);
        af[4] = (short)f2bf(u1.x); af[5] = (short)f2bf(u1.y);
        af[6] = (short)f2bf(u1.z); af[7] = (short)f2bf(u1.w);
        #pragma unroll
        for (int nt = 0; nt < 4; ++nt) {
            bf16x8 bf = *reinterpret_cast<const bf16x8*>(&Wl[((ks * 4 + nt) * 64 + lane) * 8]);
            acc[nt] = __builtin_amdgcn_mfma_f32_16x16x32_bf16(af, bf, acc[nt], 0, 0, 0);
        }
    }
    // D layout: col = lane&15 (=m), row = g*4 + reg  [verified m89]
    #pragma unroll
    for (int r = 0; r < 4; ++r) {
        int orow = row0 + g * 4 + r;
        if (orow < N) {
            #pragma unroll
            for (int nt = 0; nt < 4; ++nt) {
                float dv = acc[nt][r];
                hb1[(size_t)orow * 64 + nt * 16 + m] = (unsigned short)f2bf(dv);
                float pa = dv * asw[nt];
                float pd = dv * adw[nt];
                pa += __shfl_xor(pa, 1); pa += __shfl_xor(pa, 2); pa += __shfl_xor(pa, 4);
                pd += __shfl_xor(pd, 1); pd += __shfl_xor(pd, 2); pd += __shfl_xor(pd, 4);
                if ((m & 7) == 0) {
                    as1[orow * 8 + nt * 2 + (m >> 3)] = pa;
                    ad1[orow * 8 + nt * 2 + (m >> 3)] = pd;
                }
            }
        }
    }
}

// ---- layer-1 attention: fixed-reference softmax (m0 = self-loop score),
// 8 lanes/edge (lane q8 = head = dim-octet), 8 edges/iter, no online rescale ----

__global__ __launch_bounds__(256) void attn1_kernel(
    const unsigned short* __restrict__ hb1, const float* __restrict__ as1,
    const float* __restrict__ ad1, const int* __restrict__ rowptr,
    const int* __restrict__ csr_src, const float* __restrict__ b1,
    float* __restrict__ helu, int N) {
    int wv = threadIdx.x >> 6;
    int lane = threadIdx.x & 63;
    int d = blockIdx.x * 4 + wv;
    if (d >= N) return;
    int beg = rowptr[d];
    int edeg = rowptr[d + 1] - beg;
    int tot = edeg + 1;  // + virtual self loop (src = d)
    int q8 = lane & 7, g = lane >> 3;
    float adh = ad1[d * 8 + q8];                  // log2-domain
    float es = as1[d * 8 + q8] + adh;             // self score
    es = fmaxf(es, NEG_SLOPE * es);
    const uint4* hb = reinterpret_cast<const uint4*>(hb1);
    float s = 0.f;
    float acc[8] = {0.f,0.f,0.f,0.f,0.f,0.f,0.f,0.f};
    for (int p0 = 0; p0 < tot; p0 += 8) {
        int p = p0 + g;
        int sn = (p < edeg) ? csr_src[beg + p] : d;
        float e = as1[sn * 8 + q8] + adh;
        e = fmaxf(e, NEG_SLOPE * e);
        float w = (p < tot) ? exp2fast(e - es) : 0.f;
        uint4 u = hb[(size_t)sn * 8 + q8];
        float f[8];
        bf8up(u, f);
        s += w;
        #pragma unroll
        for (int j = 0; j < 8; ++j) acc[j] = fmaf(w, f[j], acc[j]);
    }
    #pragma unroll
    for (int mask = 8; mask < 64; mask <<= 1) {
        s += __shfl_xor(s, mask);
        #pragma unroll
        for (int j = 0; j < 8; ++j) acc[j] += __shfl_xor(acc[j], mask);
    }
    if (lane < 8) {
        float inv = 1.f / (s + 1e-16f);
        const float4* b4 = reinterpret_cast<const float4*>(b1 + q8 * 8);
        float4 ba = b4[0], bb = b4[1];
        float o[8];
        o[0] = fmaf(acc[0], inv, ba.x); o[1] = fmaf(acc[1], inv, ba.y);
        o[2] = fmaf(acc[2], inv, ba.z); o[3] = fmaf(acc[3], inv, ba.w);
        o[4] = fmaf(acc[4], inv, bb.x); o[5] = fmaf(acc[5], inv, bb.y);
        o[6] = fmaf(acc[6], inv, bb.z); o[7] = fmaf(acc[7], inv, bb.w);
        #pragma unroll
        for (int j = 0; j < 8; ++j) o[j] = (o[j] > 0.f) ? o[j] : (__expf(o[j]) - 1.f);
        float4 r0, r1;
        r0.x = o[0]; r0.y = o[1]; r0.z = o[2]; r0.w = o[3];
        r1.x = o[4]; r1.y = o[5]; r1.z = o[6]; r1.w = o[7];
        *reinterpret_cast<float4*>(&helu[(size_t)d * 64 + q8 * 8]) = r0;
        *reinterpret_cast<float4*>(&helu[(size_t)d * 64 + q8 * 8 + 4]) = r1;
    }
}

// ---- GEMM2 (64x64) + alpha2 (pre-scaled by LOG2E), one wave per row; bf16 h2 out ----

__global__ __launch_bounds__(256) void gemm2_kernel(
    const float* __restrict__ helu, const float* __restrict__ W2,
    const float* __restrict__ a_src2, const float* __restrict__ a_dst2,
    unsigned short* __restrict__ hb2, float* __restrict__ as2, float* __restrict__ ad2, int N) {
    __shared__ float Ws[64 * 64];
    __shared__ float asw[64], adw[64];
    int tid = threadIdx.x;
    for (int i = tid; i < 64 * 64; i += 256) Ws[i] = W2[i];
    if (tid < 64) { asw[tid] = a_src2[tid] * LOG2E; adw[tid] = a_dst2[tid] * LOG2E; }
    __syncthreads();
    int lane = tid & 63, wv = tid >> 6;
    int stride = gridDim.x * 4;
    for (int row = blockIdx.x * 4 + wv; row < N; row += stride) {
        float hv = helu[(size_t)row * 64 + lane];
        float acc = 0.f;
        #pragma unroll
        for (int k = 0; k < 64; ++k) {
            float v = __shfl(hv, k);
            acc += v * Ws[k * 64 + lane];
        }
        hb2[(size_t)row * 64 + lane] = (unsigned short)f2bf(acc);
        float pa = acc * asw[lane];
        float pb = acc * adw[lane];
        #pragma unroll
        for (int mask = 1; mask < 64; mask <<= 1) {
            pa += __shfl_xor(pa, mask);
            pb += __shfl_xor(pb, mask);
        }
        if (lane == 0) { as2[row] = pa; ad2[row] = pb; }
    }
}

// ---- layer-2 attention + log_softmax: fixed-reference softmax, 8 lanes/edge ----

__global__ __launch_bounds__(256) void attn2_kernel(
    const unsigned short* __restrict__ hb2, const float* __restrict__ as2,
    const float* __restrict__ ad2, const int* __restrict__ rowptr,
    const int* __restrict__ csr_src, const float* __restrict__ b2,
    float* __restrict__ out, int N) {
    int wv = threadIdx.x >> 6;
    int lane = threadIdx.x & 63;
    int d = blockIdx.x * 4 + wv;
    if (d >= N) return;
    int beg = rowptr[d];
    int edeg = rowptr[d + 1] - beg;
    int tot = edeg + 1;
    int q8 = lane & 7, g = lane >> 3;
    float add = ad2[d];                           // log2-domain
    float es = as2[d] + add;
    es = fmaxf(es, NEG_SLOPE * es);
    const uint4* hb = reinterpret_cast<const uint4*>(hb2);
    float s = 0.f;
    float acc[8] = {0.f,0.f,0.f,0.f,0.f,0.f,0.f,0.f};
    for (int p0 = 0; p0 < tot; p0 += 8) {
        int p = p0 + g;
        int sn = (p < edeg) ? csr_src[beg + p] : d;
        float e = as2[sn] + add;
        e = fmaxf(e, NEG_SLOPE * e);
        float w = (p < tot) ? exp2fast(e - es) : 0.f;
        uint4 u = hb[(size_t)sn * 8 + q8];
        float f[8];
        bf8up(u, f);
        s += w;
        #pragma unroll
        for (int j = 0; j < 8; ++j) acc[j] = fmaf(w, f[j], acc[j]);
    }
    #pragma unroll
    for (int mask = 8; mask < 64; mask <<= 1) {
        s += __shfl_xor(s, mask);
        #pragma unroll
        for (int j = 0; j < 8; ++j) acc[j] += __shfl_xor(acc[j], mask);
    }
    // all lanes now hold full s / acc (xor-reduce broadcasts)
    float inv = 1.f / (s + 1e-16f);
    const float4* b4 = reinterpret_cast<const float4*>(b2 + q8 * 8);
    float4 ba = b4[0], bb = b4[1];
    float o[8];
    o[0] = fmaf(acc[0], inv, ba.x); o[1] = fmaf(acc[1], inv, ba.y);
    o[2] = fmaf(acc[2], inv, ba.z); o[3] = fmaf(acc[3], inv, ba.w);
    o[4] = fmaf(acc[4], inv, bb.x); o[5] = fmaf(acc[5], inv, bb.y);
    o[6] = fmaf(acc[6], inv, bb.z); o[7] = fmaf(acc[7], inv, bb.w);
    // log_softmax over 64 dims: 8 in-lane + across the 8 q8 lanes (masks 1,2,4)
    float mx = o[0];
    #pragma unroll
    for (int j = 1; j < 8; ++j) mx = fmaxf(mx, o[j]);
    #pragma unroll
    for (int mask = 1; mask < 8; mask <<= 1) mx = fmaxf(mx, __shfl_xor(mx, mask));
    float sm = 0.f;
    #pragma unroll
    for (int j = 0; j < 8; ++j) sm += __expf(o[j] - mx);
    #pragma unroll
    for (int mask = 1; mask < 8; mask <<= 1) sm += __shfl_xor(sm, mask);
    float lse = mx + __logf(sm);
    if (lane < 8) {
        float4 r0, r1;
        r0.x = o[0] - lse; r0.y = o[1] - lse; r0.z = o[2] - lse; r0.w = o[3] - lse;
        r1.x = o[4] - lse; r1.y = o[5] - lse; r1.z = o[6] - lse; r1.w = o[7] - lse;
        *reinterpret_cast<float4*>(&out[(size_t)d * 64 + q8 * 8]) = r0;
        *reinterpret_cast<float4*>(&out[(size_t)d * 64 + q8 * 8 + 4]) = r1;
    }
}

// ---------------- launch ----------------

extern "C" void kernel_launch(void* const* d_in, const int* in_sizes, int n_in,
                              void* d_out, int out_size, void* d_ws, size_t ws_size,
                              hipStream_t stream) {
    const float* x      = (const float*)d_in[0];
    const int*   ei     = (const int*)d_in[1];
    const float* W1     = (const float*)d_in[2];
    const float* a_src1 = (const float*)d_in[3];
    const float* a_dst1 = (const float*)d_in[4];
    const float* b1     = (const float*)d_in[5];
    const float* W2     = (const float*)d_in[6];
    const float* a_src2 = (const float*)d_in[7];
    const float* a_dst2 = (const float*)d_in[8];
    const float* b2     = (const float*)d_in[9];

    int N = in_sizes[0] / 512;
    int E = in_sizes[1] / 2;
    const int* src = ei;
    const int* dst = ei + E;
    int NB = (N + 255) >> NB_SHIFT;          // 391 buckets of 256 nodes

    char* w = (char*)d_ws;
    size_t off = 0;
    auto alloc = [&](size_t bytes) -> void* {
        off = (off + 255) & ~(size_t)255;
        void* p = w + off;
        off += bytes;
        return p;
    };
    int* bcnt   = (int*)alloc((size_t)NB * sizeof(int));
    int* rowptr = (int*)alloc((size_t)(N + 1) * sizeof(int));
    int* bbase  = (int*)alloc((size_t)(NB + 1) * sizeof(int));
    int* bcur   = (int*)alloc((size_t)NB * sizeof(int));
    int* csr    = (int*)alloc((size_t)E * sizeof(int));
    unsigned short* hb1 = (unsigned short*)alloc((size_t)N * 64 * sizeof(unsigned short));
    float* as1  = (float*)alloc((size_t)N * 8 * sizeof(float));
    float* ad1  = (float*)alloc((size_t)N * 8 * sizeof(float));
    float* helu = (float*)alloc((size_t)N * 64 * sizeof(float));
    uint2* pairs = (uint2*)helu;             // alias: pairs dead before attn1 writes helu
    unsigned short* hb2 = hb1;               // aliases: hb1/as1/ad1 dead after attn1
    float* as2 = as1;
    float* ad2 = ad1;

    zero_int_kernel<<<(NB + 255) / 256, 256, 0, stream>>>(bcnt, NB);
    bucket_count_kernel<<<(E + 16383) / 16384, 256, 0, stream>>>(dst, E, bcnt, NB);
    scan_bucket_kernel<<<1, 512, 0, stream>>>(bcnt, NB, bbase, bcur, rowptr, N);
    bucket_scatter_kernel<<<(E + 8191) / 8192, 256, 0, stream>>>(src, dst, E, bcur, pairs, NB);
    build_csr_kernel<<<NB, 512, 0, stream>>>(pairs, bbase, rowptr, csr, N);

    gemm1_kernel<<<(N + 127) / 128, 512, 0, stream>>>(x, W1, a_src1, a_dst1, hb1, as1, ad1, N);
    attn1_kernel<<<(N + 3) / 4, 256, 0, stream>>>(hb1, as1, ad1, rowptr, csr, b1, helu, N);

    gemm2_kernel<<<2048, 256, 0, stream>>>(helu, W2, a_src2, a_dst2, hb2, as2, ad2, N);
    attn2_kernel<<<(N + 3) / 4, 256, 0, stream>>>(hb2, as2, ad2, rowptr, csr, b2, (float*)d_out, N);
}